// Round 6
// baseline (522.710 us; speedup 1.0000x reference)
//
#include <hip/hip_runtime.h>
#include <hip/hip_fp16.h>
#include <cstddef>
#include <cstdint>

#define N_NODES   100000
#define N_EDGES   1600000
#define N_GRAPHS  512
#define HIDDEN    128
#define N_LAYERS  3

// 400-way counting sort (R9-confirmed). 128 place blocks (R13: ~31-edge runs
// per window -> near-full-line wedge writes).
#define N_WIN        400
#define WIN_NODES    (N_NODES / N_WIN)      // 250
#define PLACE_BLOCKS 128
#define PCHUNK       (N_EDGES / PLACE_BLOCKS)  // 12500, divisible by 4

#define F2H_BLOCKS   ((N_NODES * HIDDEN / 8) / 256)            // 6250
#define WCONV_BLOCKS (N_LAYERS * 2 * 16)                       // 96
#define GB_BLOCKS    2                                         // graph-boundary search
#define PREP_BLOCKS  (F2H_BLOCKS + WCONV_BLOCKS + GB_BLOCKS)

typedef _Float16 half8  __attribute__((ext_vector_type(8)));
typedef _Float16 half4v __attribute__((ext_vector_type(4)));
typedef _Float16 half2v __attribute__((ext_vector_type(2)));
typedef float    float8 __attribute__((ext_vector_type(8)));
typedef float    floatx4 __attribute__((ext_vector_type(4)));
typedef float    floatx2 __attribute__((ext_vector_type(2)));

// ---------------------------------------------------------------------------
__global__ __launch_bounds__(256) void win_count_kernel(const int* __restrict__ dst,
                                                        int* __restrict__ counts) {
    __shared__ int cs[N_WIN];
    for (int i = threadIdx.x; i < N_WIN; i += 256) cs[i] = 0;
    __syncthreads();
    const int4* d4 = (const int4*)(dst + blockIdx.x * PCHUNK);
    for (int i = threadIdx.x; i < PCHUNK / 4; i += 256) {
        int4 d = d4[i];
        atomicAdd(&cs[d.x / WIN_NODES], 1);
        atomicAdd(&cs[d.y / WIN_NODES], 1);
        atomicAdd(&cs[d.z / WIN_NODES], 1);
        atomicAdd(&cs[d.w / WIN_NODES], 1);
    }
    __syncthreads();
    for (int i = threadIdx.x; i < N_WIN; i += 256)
        counts[blockIdx.x * N_WIN + i] = cs[i];
}

// column scan over the 128 place-blocks; emits per-block offsets + col totals
__global__ __launch_bounds__(128) void win_scan1_kernel(const int* __restrict__ counts,
                                                        int* __restrict__ offsets,
                                                        int* __restrict__ colsum) {
    __shared__ int tmp[128];
    const int w = blockIdx.x;
    const int t = threadIdx.x;
    tmp[t] = counts[t * N_WIN + w];
    __syncthreads();
#pragma unroll
    for (int off = 1; off < 128; off <<= 1) {
        int u = (t >= off) ? tmp[t - off] : 0;
        __syncthreads();
        tmp[t] += u;
        __syncthreads();
    }
    offsets[t * N_WIN + w] = (t == 0) ? 0 : tmp[t - 1];
    if (t == 127) colsum[w] = tmp[127];
}

// place: re-derives winbase from colsum via in-LDS scan (win_scan2 removed)
__global__ __launch_bounds__(512) void win_place_kernel(const int* __restrict__ src,
                                                        const int* __restrict__ dst,
                                                        const int* __restrict__ offsets,
                                                        const int* __restrict__ colsum,
                                                        int2* __restrict__ wedge) {
    __shared__ int ws[512];
    __shared__ int off[N_WIN];
    const int t = threadIdx.x;
    ws[t] = (t < N_WIN) ? colsum[t] : 0;
    __syncthreads();
#pragma unroll
    for (int o = 1; o < 512; o <<= 1) {
        int u = (t >= o) ? ws[t - o] : 0;
        __syncthreads();
        ws[t] += u;
        __syncthreads();
    }
    if (t < N_WIN) off[t] = offsets[blockIdx.x * N_WIN + t] + ((t == 0) ? 0 : ws[t - 1]);
    __syncthreads();
    const int4* d4 = (const int4*)(dst + blockIdx.x * PCHUNK);
    const int4* s4 = (const int4*)(src + blockIdx.x * PCHUNK);
    for (int i = t; i < PCHUNK / 4; i += 512) {
        int4 d = d4[i];
        int4 s = s4[i];
        int p0 = atomicAdd(&off[d.x / WIN_NODES], 1); wedge[p0] = make_int2(d.x, s.x);
        int p1 = atomicAdd(&off[d.y / WIN_NODES], 1); wedge[p1] = make_int2(d.y, s.y);
        int p2 = atomicAdd(&off[d.z / WIN_NODES], 1); wedge[p2] = make_int2(d.z, s.z);
        int p3 = atomicAdd(&off[d.w / WIN_NODES], 1); wedge[p3] = make_int2(d.w, s.w);
    }
}

// fused per-window CSR: winbase scan -> count -> scan -> row_ptr -> scatter
__global__ __launch_bounds__(512) void win_csr_kernel(const int2* __restrict__ wedge,
                                                      const int* __restrict__ colsum,
                                                      int* __restrict__ row_ptr,
                                                      int* __restrict__ csr_src) {
    __shared__ int ws[512];
    __shared__ int cnt[WIN_NODES];
    __shared__ int bb[2];
    const int w = blockIdx.x, n0 = w * WIN_NODES, t = threadIdx.x;
    ws[t] = (t < N_WIN) ? colsum[t] : 0;
    __syncthreads();
#pragma unroll
    for (int o = 1; o < 512; o <<= 1) {
        int u = (t >= o) ? ws[t - o] : 0;
        __syncthreads();
        ws[t] += u;
        __syncthreads();
    }
    if (t == 0) { bb[0] = (w > 0) ? ws[w - 1] : 0; bb[1] = ws[w]; }
    if (w == N_WIN - 1 && t == 0) row_ptr[N_NODES] = ws[N_WIN - 1];
    for (int i = t; i < WIN_NODES; i += 512) cnt[i] = 0;
    __syncthreads();
    const int b0 = bb[0], b1 = bb[1];
    for (int e = b0 + t; e < b1; e += 512)
        atomicAdd(&cnt[wedge[e].x - n0], 1);
    __syncthreads();
    ws[t] = (t < WIN_NODES) ? cnt[t] : 0;
    __syncthreads();
#pragma unroll
    for (int o = 1; o < 512; o <<= 1) {
        int u = (t >= o) ? ws[t - o] : 0;
        __syncthreads();
        ws[t] += u;
        __syncthreads();
    }
    const int excl = (t == 0) ? 0 : ws[t - 1];
    if (t < WIN_NODES) {
        row_ptr[n0 + t] = b0 + excl;
        cnt[t] = b0 + excl;
    }
    __syncthreads();
    for (int e = b0 + t; e < b1; e += 512) {
        int2 ed = wedge[e];
        int p = atomicAdd(&cnt[ed.x - n0], 1);
        csr_src[p] = ed.y;
    }
}

// ---------------------------------------------------------------------------
// prep: grid-split fusion of (a) X fp32->fp16+fp8, (b) LDS-tiled weight
// transpose, (c) graph-boundary binary search.
// ---------------------------------------------------------------------------
__global__ __launch_bounds__(256) void prep_kernel(const float* __restrict__ X,
                                                   __half* __restrict__ hA,
                                                   unsigned char* __restrict__ outq,
                                                   const float* __restrict__ w1,
                                                   const float* __restrict__ w2,
                                                   __half* __restrict__ wt1,
                                                   __half* __restrict__ wt2,
                                                   const int* __restrict__ batch,
                                                   int* __restrict__ gstart) {
    __shared__ float tile[32][33];
    const int b = blockIdx.x;
    if (b < F2H_BLOCKS) {
        int t = b * 256 + threadIdx.x;
        const float4* in4 = (const float4*)X;
        float4 a = in4[t * 2 + 0];
        float4 c = in4[t * 2 + 1];
        __half2* o2 = (__half2*)hA;
        o2[t * 4 + 0] = __floats2half2_rn(a.x, a.y);
        o2[t * 4 + 1] = __floats2half2_rn(a.z, a.w);
        o2[t * 4 + 2] = __floats2half2_rn(c.x, c.y);
        o2[t * 4 + 3] = __floats2half2_rn(c.z, c.w);
        unsigned r0 = 0, r1 = 0;
        r0 = __builtin_amdgcn_cvt_pk_fp8_f32(a.x, a.y, r0, false);
        r0 = __builtin_amdgcn_cvt_pk_fp8_f32(a.z, a.w, r0, true);
        r1 = __builtin_amdgcn_cvt_pk_fp8_f32(c.x, c.y, r1, false);
        r1 = __builtin_amdgcn_cvt_pk_fp8_f32(c.z, c.w, r1, true);
        ((uint2*)outq)[t] = make_uint2(r0, r1);
    } else if (b < F2H_BLOCKS + WCONV_BLOCKS) {
        const int bb = b - F2H_BLOCKS;
        const int mat = bb & 1;
        const int tt = (bb >> 1) & 15;
        const int l  = bb >> 5;
        const int ti = (tt >> 2) * 32, tj = (tt & 3) * 32;
        const float* W = (mat ? w2 : w1) + (size_t)l * HIDDEN * HIDDEN;
        __half* WT = (mat ? wt2 : wt1) + (size_t)l * HIDDEN * HIDDEN;
        const int r = threadIdx.x >> 5;
        const int c = threadIdx.x & 31;
#pragma unroll
        for (int rr = 0; rr < 4; ++rr)
            tile[r + 8 * rr][c] = W[(size_t)(ti + r + 8 * rr) * HIDDEN + tj + c];
        __syncthreads();
#pragma unroll
        for (int rr = 0; rr < 4; ++rr)
            WT[(size_t)(tj + r + 8 * rr) * HIDDEN + ti + c] =
                __float2half(tile[c][r + 8 * rr]);
    } else {
        // graph-boundary search: gstart[g] = lower_bound(batch, g)
        const int g = (b - F2H_BLOCKS - WCONV_BLOCKS) * 256 + threadIdx.x;  // 0..511
        if (g < N_GRAPHS) {
            int lo = 0, hi = N_NODES;
            while (lo < hi) {
                int mid = (lo + hi) >> 1;
                if (batch[mid] < g) lo = mid + 1; else hi = mid;
            }
            gstart[g] = lo;
        }
        if (g == 0) gstart[N_GRAPHS] = N_NODES;
    }
}

// ---------------------------------------------------------------------------
// GIN aggregation, fp8 neighbors, packed-fp16 butterfly (R12/R13-confirmed).
// ---------------------------------------------------------------------------
__device__ __forceinline__ void acc_fp8x16(float* acc, uint4 v) {
    floatx2 f;
    f = __builtin_amdgcn_cvt_pk_f32_fp8(v.x, false); acc[0] += f.x;  acc[1] += f.y;
    f = __builtin_amdgcn_cvt_pk_f32_fp8(v.x, true);  acc[2] += f.x;  acc[3] += f.y;
    f = __builtin_amdgcn_cvt_pk_f32_fp8(v.y, false); acc[4] += f.x;  acc[5] += f.y;
    f = __builtin_amdgcn_cvt_pk_f32_fp8(v.y, true);  acc[6] += f.x;  acc[7] += f.y;
    f = __builtin_amdgcn_cvt_pk_f32_fp8(v.z, false); acc[8] += f.x;  acc[9] += f.y;
    f = __builtin_amdgcn_cvt_pk_f32_fp8(v.z, true);  acc[10] += f.x; acc[11] += f.y;
    f = __builtin_amdgcn_cvt_pk_f32_fp8(v.w, false); acc[12] += f.x; acc[13] += f.y;
    f = __builtin_amdgcn_cvt_pk_f32_fp8(v.w, true);  acc[14] += f.x; acc[15] += f.y;
}

__device__ __forceinline__ void gather_body(int wave, int lane,
                                            const unsigned char* __restrict__ Xq,
                                            const __half* __restrict__ Xh,
                                            __half* __restrict__ Zh,
                                            const int* __restrict__ row_ptr,
                                            const int* __restrict__ csr_src) {
    const int grp = lane >> 3;     // 0..7
    const int m   = lane & 7;      // 0..7
    const uint4* Q = (const uint4*)Xq;   // row = 8 x uint4 (128B)

    float acc[16];
#pragma unroll
    for (int j = 0; j < 16; ++j) acc[j] = 0.f;

    int k = row_ptr[wave];
    const int end = row_ptr[wave + 1];

    for (; k + 16 <= end; k += 16) {
        int n0 = csr_src[k + grp];
        int n1 = csr_src[k + 8 + grp];
        uint4 v0 = Q[(size_t)n0 * 8 + m];
        uint4 v1 = Q[(size_t)n1 * 8 + m];
        acc_fp8x16(acc, v0);
        acc_fp8x16(acc, v1);
    }
    if (k + 8 <= end) {
        int n0 = csr_src[k + grp];
        uint4 v0 = Q[(size_t)n0 * 8 + m];
        acc_fp8x16(acc, v0);
        k += 8;
    }
    int rem = end - k;
    if (grp < rem) {
        int n0 = csr_src[k + grp];
        uint4 v0 = Q[(size_t)n0 * 8 + m];
        acc_fp8x16(acc, v0);
    }

    half2v hh[8];
#pragma unroll
    for (int j = 0; j < 8; ++j) {
        hh[j][0] = (_Float16)acc[2 * j];
        hh[j][1] = (_Float16)acc[2 * j + 1];
    }
#pragma unroll
    for (int j = 0; j < 8; ++j) {
        int b = __shfl_xor(__builtin_bit_cast(int, hh[j]), 8);
        hh[j] = hh[j] + __builtin_bit_cast(half2v, b);
    }
#pragma unroll
    for (int j = 0; j < 8; ++j) {
        int b = __shfl_xor(__builtin_bit_cast(int, hh[j]), 16);
        hh[j] = hh[j] + __builtin_bit_cast(half2v, b);
    }
#pragma unroll
    for (int j = 0; j < 8; ++j) {
        int b = __shfl_xor(__builtin_bit_cast(int, hh[j]), 32);
        hh[j] = hh[j] + __builtin_bit_cast(half2v, b);
    }

    if (grp == 0) {
        const half2v* H2 = (const half2v*)(Xh + (size_t)wave * HIDDEN + 16 * m);
        half8 o0, o1;
#pragma unroll
        for (int j = 0; j < 4; ++j) {
            half2v s = hh[j] + H2[j];
            o0[2 * j] = s[0]; o0[2 * j + 1] = s[1];
        }
#pragma unroll
        for (int j = 0; j < 4; ++j) {
            half2v s = hh[4 + j] + H2[4 + j];
            o1[2 * j] = s[0]; o1[2 * j + 1] = s[1];
        }
        ((half8*)(Zh + (size_t)wave * HIDDEN + 16 * m))[0] = o0;
        ((half8*)(Zh + (size_t)wave * HIDDEN + 16 * m))[1] = o1;
    }
}

__global__ void gather_kernel(const unsigned char* __restrict__ Xq,
                              const __half* __restrict__ Xh,
                              __half* __restrict__ Zh,
                              const int* __restrict__ row_ptr,
                              const int* __restrict__ csr_src) {
    int wave = (blockIdx.x * blockDim.x + threadIdx.x) >> 6;
    if (wave >= N_NODES) return;
    gather_body(wave, threadIdx.x & 63, Xq, Xh, Zh, row_ptr, csr_src);
}

// ---------------------------------------------------------------------------
// Atomic-free global pooling (R15-confirmed). One block per graph.
// ---------------------------------------------------------------------------
__device__ __forceinline__ void gpool_body(int g,
                                           const __half* __restrict__ Xh,
                                           const int* __restrict__ gstart,
                                           float* __restrict__ pooled, int layer) {
    __shared__ float red[16][16][8];   // 8 KiB
    const int f8 = threadIdx.x & 15;   // col group: cols f8*8 .. f8*8+7
    const int qt = threadIdx.x >> 4;   // row phase 0..15
    const int s = gstart[g], e = gstart[g + 1];

    float acc[8];
#pragma unroll
    for (int j = 0; j < 8; ++j) acc[j] = 0.f;

    for (int n = s + qt; n < e; n += 16) {
        half8 v = ((const half8*)(Xh + (size_t)n * HIDDEN))[f8];
#pragma unroll
        for (int j = 0; j < 8; ++j) acc[j] += (float)v[j];
    }
#pragma unroll
    for (int j = 0; j < 8; ++j) red[qt][f8][j] = acc[j];
    __syncthreads();

    if (threadIdx.x < 128) {
        const int c = threadIdx.x;
        float sum = 0.f;
#pragma unroll
        for (int p = 0; p < 16; ++p) sum += red[p][c >> 3][c & 7];
        pooled[(size_t)g * (HIDDEN * N_LAYERS) + layer * HIDDEN + c] = sum;
    }
}

__global__ __launch_bounds__(256) void gpool_kernel(const __half* __restrict__ Xh,
                                                    const int* __restrict__ gstart,
                                                    float* __restrict__ pooled,
                                                    int layer) {
    gpool_body(blockIdx.x, Xh, gstart, pooled, layer);
}

// gather(l) + gpool(l-1) grid-split fusion (R16): both consume the same mm2
// output; pool blocks FIRST so their streaming rides under gather's
// latency-bound phase. Saves 2 dispatches + hides ~2x10us of pool time.
#define POOL_BLKS N_GRAPHS   // 512
__global__ __launch_bounds__(256) void gather_pool_kernel(const unsigned char* __restrict__ Xq,
                                                          const __half* __restrict__ Xh,
                                                          __half* __restrict__ Zh,
                                                          const int* __restrict__ row_ptr,
                                                          const int* __restrict__ csr_src,
                                                          const int* __restrict__ gstart,
                                                          float* __restrict__ pooled,
                                                          int prev_layer) {
    if (blockIdx.x < POOL_BLKS) {
        gpool_body(blockIdx.x, Xh, gstart, pooled, prev_layer);
        return;
    }
    int wave = ((blockIdx.x - POOL_BLKS) * 256 + threadIdx.x) >> 6;
    if (wave >= N_NODES) return;
    gather_body(wave, threadIdx.x & 63, Xq, Xh, Zh, row_ptr, csr_src);
}

// ---------------------------------------------------------------------------
// Fused MLP (R18): mm1 + mm2 in ONE kernel, NO atomics, NO pooling.
// R5 post-mortem: VGPR pinned at the 128 boundary with ~40 slots spilled to
// scratch -> 150 MB/dispatch phantom HBM traffic (FETCH 110/WRITE 103 vs
// 26/38 needed). This revision cuts register pressure:
//  - biases moved to LDS (bs[2][128], 1 KB): -64 VGPRs vs bl1/bl2 arrays.
//  - mm1 restructured per c-pair: compute hh[2c],hh[2c+1], shuffle into hf[c]
//    immediately (wave lockstep makes the shuffle valid) -> peak live hh is
//    4 regs, not 16.
//  - A prefetch kept (16 regs, now affordable; est. total ~95 VGPRs).
// Swizzle + shuffle layout proven in R5 (absmax 32).
// ---------------------------------------------------------------------------
#define MM_BLOCKS 512
__global__ __launch_bounds__(256, 2) void mlp2_kernel(const __half* __restrict__ A,
                                                      const __half* __restrict__ Wt1,
                                                      const __half* __restrict__ Wt2,
                                                      const float* __restrict__ b1,
                                                      const float* __restrict__ b2,
                                                      __half* __restrict__ C16,
                                                      unsigned char* __restrict__ Q8) {
    __shared__ __half w1s[128][128];   // 32 KiB, XOR-swizzled 16B chunks
    __shared__ __half w2s[128][128];   // 32 KiB
    __shared__ float  bs[2][128];      // 1 KiB

    const int tid  = threadIdx.x;
    const int lane = tid & 63;
    const int m    = lane & 15;
    const int q    = lane >> 4;

    // stage weights (coalesced 16B loads; swizzled 16B LDS writes) + biases
    {
        const half8* s1 = (const half8*)Wt1;
        const half8* s2 = (const half8*)Wt2;
        for (int j = tid; j < 128 * 16; j += 256) {
            int r  = j >> 4;
            int cs = (j & 15) ^ (r & 15);
            *(half8*)&w1s[r][cs * 8] = s1[j];
            *(half8*)&w2s[r][cs * 8] = s2[j];
        }
        if (tid < 128) { bs[0][tid] = b1[tid]; bs[1][tid] = b2[tid]; }
    }
    __syncthreads();

    const int gwave  = (blockIdx.x * 256 + tid) >> 6;
    const int nwaves = MM_BLOCKS * 4;
    const int NTILES = N_NODES / 16;   // 6250

    const int src0 = m + ((lane & 16) << 1);  // m + 32*(q&1)
    const int src1 = src0 + 16;
    const bool sel = ((lane >> 5) & 1) != 0;  // q>>1

    if (gwave >= NTILES) return;

    // prime tile 0
    int t = gwave;
    half8 a0, a1, a2, a3;
    {
        const half8* Arow = (const half8*)(A + (size_t)(t * 16 + m) * HIDDEN);
        a0 = Arow[q]; a1 = Arow[4 + q]; a2 = Arow[8 + q]; a3 = Arow[12 + q];
    }

    while (true) {
        const int tn = t + nwaves;
        half8 n0, n1, n2, n3;
        if (tn < NTILES) {   // prefetch next tile (wave-uniform branch)
            const half8* Nrow = (const half8*)(A + (size_t)(tn * 16 + m) * HIDDEN);
            n0 = Nrow[q]; n1 = Nrow[4 + q]; n2 = Nrow[8 + q]; n3 = Nrow[12 + q];
        }

        // ---- mm1 + redistribute, one c-pair at a time (low live range).
        // For c in 0..3: hh pair (ct=2c, 2c+1) -> shuffle both banks from
        // both source lanes -> select by destination's sel (R4 bug fix).
        half8 hf[4];
#pragma unroll
        for (int c = 0; c < 4; ++c) {
            unsigned px[2], py[2];
#pragma unroll
            for (int s = 0; s < 2; ++s) {
                const int ct = 2 * c + s;
                const _Float16* wrow = (const _Float16*)&w1s[ct * 16 + m][0];
                floatx4 acc = {0.f, 0.f, 0.f, 0.f};
                acc = __builtin_amdgcn_mfma_f32_16x16x32_f16(*(const half8*)(wrow + (((0 + q) ^ m) * 8)),  a0, acc, 0, 0, 0);
                acc = __builtin_amdgcn_mfma_f32_16x16x32_f16(*(const half8*)(wrow + (((4 + q) ^ m) * 8)),  a1, acc, 0, 0, 0);
                acc = __builtin_amdgcn_mfma_f32_16x16x32_f16(*(const half8*)(wrow + (((8 + q) ^ m) * 8)),  a2, acc, 0, 0, 0);
                acc = __builtin_amdgcn_mfma_f32_16x16x32_f16(*(const half8*)(wrow + (((12 + q) ^ m) * 8)), a3, acc, 0, 0, 0);
                const floatx4 bb = *(const floatx4*)&bs[0][ct * 16 + q * 4];
                half2v p0, p1;
                p0[0] = (_Float16)fmaxf(acc[0] + bb[0], 0.f);
                p0[1] = (_Float16)fmaxf(acc[1] + bb[1], 0.f);
                p1[0] = (_Float16)fmaxf(acc[2] + bb[2], 0.f);
                p1[1] = (_Float16)fmaxf(acc[3] + bb[3], 0.f);
                px[s] = __builtin_bit_cast(unsigned, p0);
                py[s] = __builtin_bit_cast(unsigned, p1);
            }
            unsigned ax = (unsigned)__shfl((int)px[0], src0);
            unsigned ay = (unsigned)__shfl((int)py[0], src0);
            unsigned az = (unsigned)__shfl((int)px[0], src1);
            unsigned aw = (unsigned)__shfl((int)py[0], src1);
            unsigned bx = (unsigned)__shfl((int)px[1], src0);
            unsigned by = (unsigned)__shfl((int)py[1], src0);
            unsigned bz = (unsigned)__shfl((int)px[1], src1);
            unsigned bw = (unsigned)__shfl((int)py[1], src1);
            uint4 u;
            u.x = sel ? bx : ax;
            u.y = sel ? by : ay;
            u.z = sel ? bz : az;
            u.w = sel ? bw : aw;
            hf[c] = __builtin_bit_cast(half8, u);
        }

        // ---- mm2: out = relu(h @ W2 + b2) -> fp16 store + optional fp8 twin
        __half* Cr = C16 + (size_t)(t * 16 + m) * HIDDEN + q * 4;
#pragma unroll
        for (int ct = 0; ct < 8; ++ct) {
            const _Float16* wrow = (const _Float16*)&w2s[ct * 16 + m][0];
            floatx4 acc = {0.f, 0.f, 0.f, 0.f};
            acc = __builtin_amdgcn_mfma_f32_16x16x32_f16(*(const half8*)(wrow + (((0 + q) ^ m) * 8)),  hf[0], acc, 0, 0, 0);
            acc = __builtin_amdgcn_mfma_f32_16x16x32_f16(*(const half8*)(wrow + (((4 + q) ^ m) * 8)),  hf[1], acc, 0, 0, 0);
            acc = __builtin_amdgcn_mfma_f32_16x16x32_f16(*(const half8*)(wrow + (((8 + q) ^ m) * 8)),  hf[2], acc, 0, 0, 0);
            acc = __builtin_amdgcn_mfma_f32_16x16x32_f16(*(const half8*)(wrow + (((12 + q) ^ m) * 8)), hf[3], acc, 0, 0, 0);
            const floatx4 bb = *(const floatx4*)&bs[1][ct * 16 + q * 4];
            float v0 = fmaxf(acc[0] + bb[0], 0.f);
            float v1 = fmaxf(acc[1] + bb[1], 0.f);
            float v2 = fmaxf(acc[2] + bb[2], 0.f);
            float v3 = fmaxf(acc[3] + bb[3], 0.f);
            half4v o;
            o[0] = (_Float16)v0; o[1] = (_Float16)v1;
            o[2] = (_Float16)v2; o[3] = (_Float16)v3;
            *(half4v*)(Cr + ct * 16) = o;
            if (Q8) {
                unsigned r0 = 0;
                r0 = __builtin_amdgcn_cvt_pk_fp8_f32(v0, v1, r0, false);
                r0 = __builtin_amdgcn_cvt_pk_fp8_f32(v2, v3, r0, true);
                *(unsigned*)(Q8 + (size_t)(t * 16 + m) * HIDDEN + ct * 16 + q * 4) = r0;
            }
        }

        if (tn >= NTILES) break;
        t = tn;
        a0 = n0; a1 = n1; a2 = n2; a3 = n3;
    }
}

// ---------------------------------------------------------------------------
__global__ __launch_bounds__(128) void cls_kernel(const float* __restrict__ pooled,
                                                  const float* __restrict__ w1,
                                                  const float* __restrict__ b1,
                                                  const float* __restrict__ w2,
                                                  const float* __restrict__ b2,
                                                  const float* __restrict__ w3,
                                                  const float* __restrict__ b3,
                                                  float* __restrict__ out) {
    __shared__ float hin[HIDDEN * N_LAYERS];
    __shared__ float h1[HIDDEN];
    __shared__ float red[HIDDEN];
    const int g = blockIdx.x;
    const int t = threadIdx.x;

    for (int i = t; i < HIDDEN * N_LAYERS; i += 128)
        hin[i] = pooled[(size_t)g * (HIDDEN * N_LAYERS) + i];
    __syncthreads();

    float s = 0.f;
    for (int k = 0; k < HIDDEN * N_LAYERS; ++k) s += hin[k] * w1[(size_t)k * HIDDEN + t];
    s = fmaxf(s + b1[t], 0.f);
    h1[t] = s;
    __syncthreads();

    float s2 = 0.f;
    for (int k = 0; k < HIDDEN; ++k) s2 += h1[k] * w2[(size_t)k * HIDDEN + t];
    s2 = fmaxf(s2 + b2[t], 0.f);

    red[t] = s2 * w3[t];
    __syncthreads();
    for (int off = 64; off > 0; off >>= 1) {
        if (t < off) red[t] += red[t + off];
        __syncthreads();
    }
    if (t == 0) out[g] = red[0] + b3[0];
}

// ---------------------------------------------------------------------------
extern "C" void kernel_launch(void* const* d_in, const int* in_sizes, int n_in,
                              void* d_out, int out_size, void* d_ws, size_t ws_size,
                              hipStream_t stream) {
    const float* X     = (const float*)d_in[0];
    const int*   ei    = (const int*)d_in[1];
    const int*   batch = (const int*)d_in[2];
    const float* w1all = (const float*)d_in[3];
    const float* b1all = (const float*)d_in[4];
    const float* w2all = (const float*)d_in[5];
    const float* b2all = (const float*)d_in[6];
    const float* cw1   = (const float*)d_in[7];
    const float* cb1   = (const float*)d_in[8];
    const float* cw2   = (const float*)d_in[9];
    const float* cb2   = (const float*)d_in[10];
    const float* cw3   = (const float*)d_in[11];
    const float* cb3   = (const float*)d_in[12];
    float* out = (float*)d_out;

    const int* src = ei;
    const int* dst = ei + N_EDGES;

    char* p = (char*)d_ws;
    auto alloc2 = [&](size_t bytes) {
        char* r = p;
        p += (bytes + 255) & ~(size_t)255;
        return r;
    };
    __half* hA      = (__half*)alloc2((size_t)N_NODES * HIDDEN * sizeof(__half));
    __half* hB      = (__half*)alloc2((size_t)N_NODES * HIDDEN * sizeof(__half));
    __half* zh      = (__half*)alloc2((size_t)N_NODES * HIDDEN * sizeof(__half));
    unsigned char* qbuf = (unsigned char*)alloc2((size_t)N_NODES * HIDDEN);
    __half* wt1     = (__half*)alloc2((size_t)N_LAYERS * HIDDEN * HIDDEN * sizeof(__half));
    __half* wt2     = (__half*)alloc2((size_t)N_LAYERS * HIDDEN * HIDDEN * sizeof(__half));
    int2*   wedge   = (int2*)alloc2((size_t)N_EDGES * sizeof(int2));
    int*    csr     = (int*)alloc2((size_t)N_EDGES * sizeof(int));
    int*    rowp    = (int*)alloc2((size_t)(N_NODES + 1) * sizeof(int));
    int*    counts  = (int*)alloc2((size_t)PLACE_BLOCKS * N_WIN * sizeof(int));
    int*    offsets = (int*)alloc2((size_t)PLACE_BLOCKS * N_WIN * sizeof(int));
    int*    colsum  = (int*)alloc2((size_t)N_WIN * sizeof(int));
    int*    gstart  = (int*)alloc2((size_t)(N_GRAPHS + 1) * sizeof(int));
    float*  pooled  = (float*)alloc2((size_t)N_GRAPHS * HIDDEN * N_LAYERS * sizeof(float));

    // CSR build: count -> column scan -> place -> fused per-window csr
    win_count_kernel<<<PLACE_BLOCKS, 256, 0, stream>>>(dst, counts);
    win_scan1_kernel<<<N_WIN, 128, 0, stream>>>(counts, offsets, colsum);
    win_place_kernel<<<PLACE_BLOCKS, 512, 0, stream>>>(src, dst, offsets, colsum, wedge);
    win_csr_kernel<<<N_WIN, 512, 0, stream>>>(wedge, colsum, rowp, csr);

    // fused prep: X conversions + weight transpose + graph-boundary search
    prep_kernel<<<PREP_BLOCKS, 256, 0, stream>>>(X, hA, qbuf, w1all, w2all, wt1, wt2,
                                                 batch, gstart);

    const int gat_grid = (N_NODES + 3) / 4;           // 25000

    __half* hcur = hA;
    for (int l = 0; l < N_LAYERS; ++l) {
        __half* hnext = (l & 1) ? hA : hB;
        const bool emit = (l < N_LAYERS - 1);
        if (l == 0) {
            gather_kernel<<<gat_grid, 256, 0, stream>>>(qbuf, hcur, zh, rowp, csr);
        } else {
            // gather(l) + gpool(l-1): both consume hcur (= mm2 output of l-1)
            gather_pool_kernel<<<gat_grid + POOL_BLKS, 256, 0, stream>>>(
                qbuf, hcur, zh, rowp, csr, gstart, pooled, l - 1);
        }
        mlp2_kernel<<<MM_BLOCKS, 256, 0, stream>>>(zh,
                                                   wt1 + (size_t)l * HIDDEN * HIDDEN,
                                                   wt2 + (size_t)l * HIDDEN * HIDDEN,
                                                   b1all + (size_t)l * HIDDEN,
                                                   b2all + (size_t)l * HIDDEN,
                                                   hnext,
                                                   emit ? qbuf : (unsigned char*)nullptr);
        hcur = hnext;
    }

    gpool_kernel<<<N_GRAPHS, 256, 0, stream>>>(hcur, gstart, pooled, N_LAYERS - 1);
    cls_kernel<<<N_GRAPHS, 128, 0, stream>>>(pooled, cw1, cb1, cw2, cb2, cw3, cb3, out);
}

// Round 7
// 462.464 us; speedup vs baseline: 1.1303x; 1.1303x over previous
//
#include <hip/hip_runtime.h>
#include <hip/hip_fp16.h>
#include <cstddef>
#include <cstdint>

#define N_NODES   100000
#define N_EDGES   1600000
#define N_GRAPHS  512
#define HIDDEN    128
#define N_LAYERS  3

// 400-way counting sort (R9-confirmed). 128 place blocks (R13: ~31-edge runs
// per window -> near-full-line wedge writes).
#define N_WIN        400
#define WIN_NODES    (N_NODES / N_WIN)      // 250
#define PLACE_BLOCKS 128
#define PCHUNK       (N_EDGES / PLACE_BLOCKS)  // 12500, divisible by 4

#define F2H_BLOCKS   ((N_NODES * HIDDEN / 8) / 256)            // 6250
#define WCONV_BLOCKS (N_LAYERS * 2 * 16)                       // 96
#define GB_BLOCKS    2                                         // graph-boundary search
#define PREP_BLOCKS  (F2H_BLOCKS + WCONV_BLOCKS + GB_BLOCKS)

typedef _Float16 half8  __attribute__((ext_vector_type(8)));
typedef _Float16 half4v __attribute__((ext_vector_type(4)));
typedef _Float16 half2v __attribute__((ext_vector_type(2)));
typedef float    float8 __attribute__((ext_vector_type(8)));
typedef float    floatx4 __attribute__((ext_vector_type(4)));
typedef float    floatx2 __attribute__((ext_vector_type(2)));

// ---------------------------------------------------------------------------
__global__ __launch_bounds__(256) void win_count_kernel(const int* __restrict__ dst,
                                                        int* __restrict__ counts) {
    __shared__ int cs[N_WIN];
    for (int i = threadIdx.x; i < N_WIN; i += 256) cs[i] = 0;
    __syncthreads();
    const int4* d4 = (const int4*)(dst + blockIdx.x * PCHUNK);
    for (int i = threadIdx.x; i < PCHUNK / 4; i += 256) {
        int4 d = d4[i];
        atomicAdd(&cs[d.x / WIN_NODES], 1);
        atomicAdd(&cs[d.y / WIN_NODES], 1);
        atomicAdd(&cs[d.z / WIN_NODES], 1);
        atomicAdd(&cs[d.w / WIN_NODES], 1);
    }
    __syncthreads();
    for (int i = threadIdx.x; i < N_WIN; i += 256)
        counts[blockIdx.x * N_WIN + i] = cs[i];
}

// column scan over the 128 place-blocks; emits per-block offsets + col totals
__global__ __launch_bounds__(128) void win_scan1_kernel(const int* __restrict__ counts,
                                                        int* __restrict__ offsets,
                                                        int* __restrict__ colsum) {
    __shared__ int tmp[128];
    const int w = blockIdx.x;
    const int t = threadIdx.x;
    tmp[t] = counts[t * N_WIN + w];
    __syncthreads();
#pragma unroll
    for (int off = 1; off < 128; off <<= 1) {
        int u = (t >= off) ? tmp[t - off] : 0;
        __syncthreads();
        tmp[t] += u;
        __syncthreads();
    }
    offsets[t * N_WIN + w] = (t == 0) ? 0 : tmp[t - 1];
    if (t == 127) colsum[w] = tmp[127];
}

// place: re-derives winbase from colsum via in-LDS scan (win_scan2 removed)
__global__ __launch_bounds__(512) void win_place_kernel(const int* __restrict__ src,
                                                        const int* __restrict__ dst,
                                                        const int* __restrict__ offsets,
                                                        const int* __restrict__ colsum,
                                                        int2* __restrict__ wedge) {
    __shared__ int ws[512];
    __shared__ int off[N_WIN];
    const int t = threadIdx.x;
    ws[t] = (t < N_WIN) ? colsum[t] : 0;
    __syncthreads();
#pragma unroll
    for (int o = 1; o < 512; o <<= 1) {
        int u = (t >= o) ? ws[t - o] : 0;
        __syncthreads();
        ws[t] += u;
        __syncthreads();
    }
    if (t < N_WIN) off[t] = offsets[blockIdx.x * N_WIN + t] + ((t == 0) ? 0 : ws[t - 1]);
    __syncthreads();
    const int4* d4 = (const int4*)(dst + blockIdx.x * PCHUNK);
    const int4* s4 = (const int4*)(src + blockIdx.x * PCHUNK);
    for (int i = t; i < PCHUNK / 4; i += 512) {
        int4 d = d4[i];
        int4 s = s4[i];
        int p0 = atomicAdd(&off[d.x / WIN_NODES], 1); wedge[p0] = make_int2(d.x, s.x);
        int p1 = atomicAdd(&off[d.y / WIN_NODES], 1); wedge[p1] = make_int2(d.y, s.y);
        int p2 = atomicAdd(&off[d.z / WIN_NODES], 1); wedge[p2] = make_int2(d.z, s.z);
        int p3 = atomicAdd(&off[d.w / WIN_NODES], 1); wedge[p3] = make_int2(d.w, s.w);
    }
}

// fused per-window CSR: winbase scan -> count -> scan -> row_ptr -> scatter
__global__ __launch_bounds__(512) void win_csr_kernel(const int2* __restrict__ wedge,
                                                      const int* __restrict__ colsum,
                                                      int* __restrict__ row_ptr,
                                                      int* __restrict__ csr_src) {
    __shared__ int ws[512];
    __shared__ int cnt[WIN_NODES];
    __shared__ int bb[2];
    const int w = blockIdx.x, n0 = w * WIN_NODES, t = threadIdx.x;
    ws[t] = (t < N_WIN) ? colsum[t] : 0;
    __syncthreads();
#pragma unroll
    for (int o = 1; o < 512; o <<= 1) {
        int u = (t >= o) ? ws[t - o] : 0;
        __syncthreads();
        ws[t] += u;
        __syncthreads();
    }
    if (t == 0) { bb[0] = (w > 0) ? ws[w - 1] : 0; bb[1] = ws[w]; }
    if (w == N_WIN - 1 && t == 0) row_ptr[N_NODES] = ws[N_WIN - 1];
    for (int i = t; i < WIN_NODES; i += 512) cnt[i] = 0;
    __syncthreads();
    const int b0 = bb[0], b1 = bb[1];
    for (int e = b0 + t; e < b1; e += 512)
        atomicAdd(&cnt[wedge[e].x - n0], 1);
    __syncthreads();
    ws[t] = (t < WIN_NODES) ? cnt[t] : 0;
    __syncthreads();
#pragma unroll
    for (int o = 1; o < 512; o <<= 1) {
        int u = (t >= o) ? ws[t - o] : 0;
        __syncthreads();
        ws[t] += u;
        __syncthreads();
    }
    const int excl = (t == 0) ? 0 : ws[t - 1];
    if (t < WIN_NODES) {
        row_ptr[n0 + t] = b0 + excl;
        cnt[t] = b0 + excl;
    }
    __syncthreads();
    for (int e = b0 + t; e < b1; e += 512) {
        int2 ed = wedge[e];
        int p = atomicAdd(&cnt[ed.x - n0], 1);
        csr_src[p] = ed.y;
    }
}

// ---------------------------------------------------------------------------
// prep: grid-split fusion of (a) X fp32->fp16+fp8, (b) LDS-tiled weight
// transpose, (c) graph-boundary binary search.
// ---------------------------------------------------------------------------
__global__ __launch_bounds__(256) void prep_kernel(const float* __restrict__ X,
                                                   __half* __restrict__ hA,
                                                   unsigned char* __restrict__ outq,
                                                   const float* __restrict__ w1,
                                                   const float* __restrict__ w2,
                                                   __half* __restrict__ wt1,
                                                   __half* __restrict__ wt2,
                                                   const int* __restrict__ batch,
                                                   int* __restrict__ gstart) {
    __shared__ float tile[32][33];
    const int b = blockIdx.x;
    if (b < F2H_BLOCKS) {
        int t = b * 256 + threadIdx.x;
        const float4* in4 = (const float4*)X;
        float4 a = in4[t * 2 + 0];
        float4 c = in4[t * 2 + 1];
        __half2* o2 = (__half2*)hA;
        o2[t * 4 + 0] = __floats2half2_rn(a.x, a.y);
        o2[t * 4 + 1] = __floats2half2_rn(a.z, a.w);
        o2[t * 4 + 2] = __floats2half2_rn(c.x, c.y);
        o2[t * 4 + 3] = __floats2half2_rn(c.z, c.w);
        unsigned r0 = 0, r1 = 0;
        r0 = __builtin_amdgcn_cvt_pk_fp8_f32(a.x, a.y, r0, false);
        r0 = __builtin_amdgcn_cvt_pk_fp8_f32(a.z, a.w, r0, true);
        r1 = __builtin_amdgcn_cvt_pk_fp8_f32(c.x, c.y, r1, false);
        r1 = __builtin_amdgcn_cvt_pk_fp8_f32(c.z, c.w, r1, true);
        ((uint2*)outq)[t] = make_uint2(r0, r1);
    } else if (b < F2H_BLOCKS + WCONV_BLOCKS) {
        const int bb = b - F2H_BLOCKS;
        const int mat = bb & 1;
        const int tt = (bb >> 1) & 15;
        const int l  = bb >> 5;
        const int ti = (tt >> 2) * 32, tj = (tt & 3) * 32;
        const float* W = (mat ? w2 : w1) + (size_t)l * HIDDEN * HIDDEN;
        __half* WT = (mat ? wt2 : wt1) + (size_t)l * HIDDEN * HIDDEN;
        const int r = threadIdx.x >> 5;
        const int c = threadIdx.x & 31;
#pragma unroll
        for (int rr = 0; rr < 4; ++rr)
            tile[r + 8 * rr][c] = W[(size_t)(ti + r + 8 * rr) * HIDDEN + tj + c];
        __syncthreads();
#pragma unroll
        for (int rr = 0; rr < 4; ++rr)
            WT[(size_t)(tj + r + 8 * rr) * HIDDEN + ti + c] =
                __float2half(tile[c][r + 8 * rr]);
    } else {
        // graph-boundary search: gstart[g] = lower_bound(batch, g)
        const int g = (b - F2H_BLOCKS - WCONV_BLOCKS) * 256 + threadIdx.x;  // 0..511
        if (g < N_GRAPHS) {
            int lo = 0, hi = N_NODES;
            while (lo < hi) {
                int mid = (lo + hi) >> 1;
                if (batch[mid] < g) lo = mid + 1; else hi = mid;
            }
            gstart[g] = lo;
        }
        if (g == 0) gstart[N_GRAPHS] = N_NODES;
    }
}

// ---------------------------------------------------------------------------
// GIN aggregation, fp8 neighbors, packed-fp16 butterfly (R12/R13-confirmed).
// ---------------------------------------------------------------------------
__device__ __forceinline__ void acc_fp8x16(float* acc, uint4 v) {
    floatx2 f;
    f = __builtin_amdgcn_cvt_pk_f32_fp8(v.x, false); acc[0] += f.x;  acc[1] += f.y;
    f = __builtin_amdgcn_cvt_pk_f32_fp8(v.x, true);  acc[2] += f.x;  acc[3] += f.y;
    f = __builtin_amdgcn_cvt_pk_f32_fp8(v.y, false); acc[4] += f.x;  acc[5] += f.y;
    f = __builtin_amdgcn_cvt_pk_f32_fp8(v.y, true);  acc[6] += f.x;  acc[7] += f.y;
    f = __builtin_amdgcn_cvt_pk_f32_fp8(v.z, false); acc[8] += f.x;  acc[9] += f.y;
    f = __builtin_amdgcn_cvt_pk_f32_fp8(v.z, true);  acc[10] += f.x; acc[11] += f.y;
    f = __builtin_amdgcn_cvt_pk_f32_fp8(v.w, false); acc[12] += f.x; acc[13] += f.y;
    f = __builtin_amdgcn_cvt_pk_f32_fp8(v.w, true);  acc[14] += f.x; acc[15] += f.y;
}

__device__ __forceinline__ void gather_body(int wave, int lane,
                                            const unsigned char* __restrict__ Xq,
                                            const __half* __restrict__ Xh,
                                            __half* __restrict__ Zh,
                                            const int* __restrict__ row_ptr,
                                            const int* __restrict__ csr_src) {
    const int grp = lane >> 3;     // 0..7
    const int m   = lane & 7;      // 0..7
    const uint4* Q = (const uint4*)Xq;   // row = 8 x uint4 (128B)

    float acc[16];
#pragma unroll
    for (int j = 0; j < 16; ++j) acc[j] = 0.f;

    int k = row_ptr[wave];
    const int end = row_ptr[wave + 1];

    for (; k + 16 <= end; k += 16) {
        int n0 = csr_src[k + grp];
        int n1 = csr_src[k + 8 + grp];
        uint4 v0 = Q[(size_t)n0 * 8 + m];
        uint4 v1 = Q[(size_t)n1 * 8 + m];
        acc_fp8x16(acc, v0);
        acc_fp8x16(acc, v1);
    }
    if (k + 8 <= end) {
        int n0 = csr_src[k + grp];
        uint4 v0 = Q[(size_t)n0 * 8 + m];
        acc_fp8x16(acc, v0);
        k += 8;
    }
    int rem = end - k;
    if (grp < rem) {
        int n0 = csr_src[k + grp];
        uint4 v0 = Q[(size_t)n0 * 8 + m];
        acc_fp8x16(acc, v0);
    }

    half2v hh[8];
#pragma unroll
    for (int j = 0; j < 8; ++j) {
        hh[j][0] = (_Float16)acc[2 * j];
        hh[j][1] = (_Float16)acc[2 * j + 1];
    }
#pragma unroll
    for (int j = 0; j < 8; ++j) {
        int b = __shfl_xor(__builtin_bit_cast(int, hh[j]), 8);
        hh[j] = hh[j] + __builtin_bit_cast(half2v, b);
    }
#pragma unroll
    for (int j = 0; j < 8; ++j) {
        int b = __shfl_xor(__builtin_bit_cast(int, hh[j]), 16);
        hh[j] = hh[j] + __builtin_bit_cast(half2v, b);
    }
#pragma unroll
    for (int j = 0; j < 8; ++j) {
        int b = __shfl_xor(__builtin_bit_cast(int, hh[j]), 32);
        hh[j] = hh[j] + __builtin_bit_cast(half2v, b);
    }

    if (grp == 0) {
        const half2v* H2 = (const half2v*)(Xh + (size_t)wave * HIDDEN + 16 * m);
        half8 o0, o1;
#pragma unroll
        for (int j = 0; j < 4; ++j) {
            half2v s = hh[j] + H2[j];
            o0[2 * j] = s[0]; o0[2 * j + 1] = s[1];
        }
#pragma unroll
        for (int j = 0; j < 4; ++j) {
            half2v s = hh[4 + j] + H2[4 + j];
            o1[2 * j] = s[0]; o1[2 * j + 1] = s[1];
        }
        ((half8*)(Zh + (size_t)wave * HIDDEN + 16 * m))[0] = o0;
        ((half8*)(Zh + (size_t)wave * HIDDEN + 16 * m))[1] = o1;
    }
}

__global__ void gather_kernel(const unsigned char* __restrict__ Xq,
                              const __half* __restrict__ Xh,
                              __half* __restrict__ Zh,
                              const int* __restrict__ row_ptr,
                              const int* __restrict__ csr_src) {
    int wave = (blockIdx.x * blockDim.x + threadIdx.x) >> 6;
    if (wave >= N_NODES) return;
    gather_body(wave, threadIdx.x & 63, Xq, Xh, Zh, row_ptr, csr_src);
}

// ---------------------------------------------------------------------------
// Atomic-free global pooling (R15-confirmed). One block per graph.
// ---------------------------------------------------------------------------
__device__ __forceinline__ void gpool_body(int g,
                                           const __half* __restrict__ Xh,
                                           const int* __restrict__ gstart,
                                           float* __restrict__ pooled, int layer) {
    __shared__ float red[16][16][8];   // 8 KiB
    const int f8 = threadIdx.x & 15;   // col group: cols f8*8 .. f8*8+7
    const int qt = threadIdx.x >> 4;   // row phase 0..15
    const int s = gstart[g], e = gstart[g + 1];

    float acc[8];
#pragma unroll
    for (int j = 0; j < 8; ++j) acc[j] = 0.f;

    for (int n = s + qt; n < e; n += 16) {
        half8 v = ((const half8*)(Xh + (size_t)n * HIDDEN))[f8];
#pragma unroll
        for (int j = 0; j < 8; ++j) acc[j] += (float)v[j];
    }
#pragma unroll
    for (int j = 0; j < 8; ++j) red[qt][f8][j] = acc[j];
    __syncthreads();

    if (threadIdx.x < 128) {
        const int c = threadIdx.x;
        float sum = 0.f;
#pragma unroll
        for (int p = 0; p < 16; ++p) sum += red[p][c >> 3][c & 7];
        pooled[(size_t)g * (HIDDEN * N_LAYERS) + layer * HIDDEN + c] = sum;
    }
}

__global__ __launch_bounds__(256) void gpool_kernel(const __half* __restrict__ Xh,
                                                    const int* __restrict__ gstart,
                                                    float* __restrict__ pooled,
                                                    int layer) {
    gpool_body(blockIdx.x, Xh, gstart, pooled, layer);
}

// gather(l) + gpool(l-1) grid-split fusion (R16-confirmed): both consume the
// same mm2 output; pool blocks FIRST so their streaming rides under gather's
// latency-bound phase.
#define POOL_BLKS N_GRAPHS   // 512
__global__ __launch_bounds__(256) void gather_pool_kernel(const unsigned char* __restrict__ Xq,
                                                          const __half* __restrict__ Xh,
                                                          __half* __restrict__ Zh,
                                                          const int* __restrict__ row_ptr,
                                                          const int* __restrict__ csr_src,
                                                          const int* __restrict__ gstart,
                                                          float* __restrict__ pooled,
                                                          int prev_layer) {
    if (blockIdx.x < POOL_BLKS) {
        gpool_body(blockIdx.x, Xh, gstart, pooled, prev_layer);
        return;
    }
    int wave = ((blockIdx.x - POOL_BLKS) * 256 + threadIdx.x) >> 6;
    if (wave >= N_NODES) return;
    gather_body(wave, threadIdx.x & 63, Xq, Xh, Zh, row_ptr, csr_src);
}

// ---------------------------------------------------------------------------
// Wave-split MFMA stage (R19). R5/R6 post-mortem: any design pushing a full
// 128x128 weight panel through ONE wave per tile spills (~150 MB phantom
// HBM traffic, VGPR pinned at 128). Fix: 4 waves per block SHARE one 16-node
// A-tile (same-CU -> L1-served, no HBM amplification); each wave owns only
// 32 output columns (ct = 2*wid, 2*wid+1) -> weight slice = 32 VGPRs,
// register-resident. No LDS, no barriers, no atomics. Math per ct identical
// to the proven mm_stage (R0/R3).
// ---------------------------------------------------------------------------
#define MM_BLOCKS 1024
__global__ __launch_bounds__(256) void mm_ws_kernel(const __half* __restrict__ A,
                                                    const __half* __restrict__ Wt,
                                                    const float* __restrict__ bias,
                                                    __half* __restrict__ C16,
                                                    unsigned char* __restrict__ Q8) {
    const int tid  = threadIdx.x;
    const int wid  = tid >> 6;         // 0..3: owns cols 32*wid .. 32*wid+31
    const int lane = tid & 63;
    const int m    = lane & 15;
    const int q    = lane >> 4;
    const int NTILES = N_NODES / 16;   // 6250

    // per-wave weight slice: 2 ct groups = 32 VGPRs + 8 bias
    half8 wf[2][4];
    float bl[2][4];
#pragma unroll
    for (int s = 0; s < 2; ++s) {
        const int ct = 2 * wid + s;
        const half8* Wrow = (const half8*)(Wt + (size_t)(ct * 16 + m) * HIDDEN);
#pragma unroll
        for (int c = 0; c < 4; ++c) wf[s][c] = Wrow[c * 4 + q];
#pragma unroll
        for (int r = 0; r < 4; ++r) bl[s][r] = bias[ct * 16 + q * 4 + r];
    }

    // prime tile 0 (all 4 waves load the same tile; L1 serves waves 1-3)
    int t = blockIdx.x;
    half8 a0, a1, a2, a3;
    {
        const half8* Arow = (const half8*)(A + (size_t)(t * 16 + m) * HIDDEN);
        a0 = Arow[q]; a1 = Arow[4 + q]; a2 = Arow[8 + q]; a3 = Arow[12 + q];
    }

    while (true) {
        const int tn = t + MM_BLOCKS;
        half8 n0, n1, n2, n3;
        if (tn < NTILES) {   // prefetch next tile (wave-uniform branch)
            const half8* Nrow = (const half8*)(A + (size_t)(tn * 16 + m) * HIDDEN);
            n0 = Nrow[q]; n1 = Nrow[4 + q]; n2 = Nrow[8 + q]; n3 = Nrow[12 + q];
        }

        __half* Cr = C16 + (size_t)(t * 16 + m) * HIDDEN + q * 4;
#pragma unroll
        for (int s = 0; s < 2; ++s) {
            const int ct = 2 * wid + s;
            floatx4 acc = {0.f, 0.f, 0.f, 0.f};
            acc = __builtin_amdgcn_mfma_f32_16x16x32_f16(wf[s][0], a0, acc, 0, 0, 0);
            acc = __builtin_amdgcn_mfma_f32_16x16x32_f16(wf[s][1], a1, acc, 0, 0, 0);
            acc = __builtin_amdgcn_mfma_f32_16x16x32_f16(wf[s][2], a2, acc, 0, 0, 0);
            acc = __builtin_amdgcn_mfma_f32_16x16x32_f16(wf[s][3], a3, acc, 0, 0, 0);
            float v0 = fmaxf(acc[0] + bl[s][0], 0.f);
            float v1 = fmaxf(acc[1] + bl[s][1], 0.f);
            float v2 = fmaxf(acc[2] + bl[s][2], 0.f);
            float v3 = fmaxf(acc[3] + bl[s][3], 0.f);
            half4v o;
            o[0] = (_Float16)v0; o[1] = (_Float16)v1;
            o[2] = (_Float16)v2; o[3] = (_Float16)v3;
            *(half4v*)(Cr + ct * 16) = o;
            if (Q8) {
                unsigned r0 = 0;
                r0 = __builtin_amdgcn_cvt_pk_fp8_f32(v0, v1, r0, false);
                r0 = __builtin_amdgcn_cvt_pk_fp8_f32(v2, v3, r0, true);
                *(unsigned*)(Q8 + (size_t)(t * 16 + m) * HIDDEN + ct * 16 + q * 4) = r0;
            }
        }

        if (tn >= NTILES) break;
        t = tn;
        a0 = n0; a1 = n1; a2 = n2; a3 = n3;
    }
}

// ---------------------------------------------------------------------------
__global__ __launch_bounds__(128) void cls_kernel(const float* __restrict__ pooled,
                                                  const float* __restrict__ w1,
                                                  const float* __restrict__ b1,
                                                  const float* __restrict__ w2,
                                                  const float* __restrict__ b2,
                                                  const float* __restrict__ w3,
                                                  const float* __restrict__ b3,
                                                  float* __restrict__ out) {
    __shared__ float hin[HIDDEN * N_LAYERS];
    __shared__ float h1[HIDDEN];
    __shared__ float red[HIDDEN];
    const int g = blockIdx.x;
    const int t = threadIdx.x;

    for (int i = t; i < HIDDEN * N_LAYERS; i += 128)
        hin[i] = pooled[(size_t)g * (HIDDEN * N_LAYERS) + i];
    __syncthreads();

    float s = 0.f;
    for (int k = 0; k < HIDDEN * N_LAYERS; ++k) s += hin[k] * w1[(size_t)k * HIDDEN + t];
    s = fmaxf(s + b1[t], 0.f);
    h1[t] = s;
    __syncthreads();

    float s2 = 0.f;
    for (int k = 0; k < HIDDEN; ++k) s2 += h1[k] * w2[(size_t)k * HIDDEN + t];
    s2 = fmaxf(s2 + b2[t], 0.f);

    red[t] = s2 * w3[t];
    __syncthreads();
    for (int off = 64; off > 0; off >>= 1) {
        if (t < off) red[t] += red[t + off];
        __syncthreads();
    }
    if (t == 0) out[g] = red[0] + b3[0];
}

// ---------------------------------------------------------------------------
extern "C" void kernel_launch(void* const* d_in, const int* in_sizes, int n_in,
                              void* d_out, int out_size, void* d_ws, size_t ws_size,
                              hipStream_t stream) {
    const float* X     = (const float*)d_in[0];
    const int*   ei    = (const int*)d_in[1];
    const int*   batch = (const int*)d_in[2];
    const float* w1all = (const float*)d_in[3];
    const float* b1all = (const float*)d_in[4];
    const float* w2all = (const float*)d_in[5];
    const float* b2all = (const float*)d_in[6];
    const float* cw1   = (const float*)d_in[7];
    const float* cb1   = (const float*)d_in[8];
    const float* cw2   = (const float*)d_in[9];
    const float* cb2   = (const float*)d_in[10];
    const float* cw3   = (const float*)d_in[11];
    const float* cb3   = (const float*)d_in[12];
    float* out = (float*)d_out;

    const int* src = ei;
    const int* dst = ei + N_EDGES;

    char* p = (char*)d_ws;
    auto alloc2 = [&](size_t bytes) {
        char* r = p;
        p += (bytes + 255) & ~(size_t)255;
        return r;
    };
    __half* hA      = (__half*)alloc2((size_t)N_NODES * HIDDEN * sizeof(__half));
    __half* hB      = (__half*)alloc2((size_t)N_NODES * HIDDEN * sizeof(__half));
    __half* zh      = (__half*)alloc2((size_t)N_NODES * HIDDEN * sizeof(__half));
    __half* m1h     = (__half*)alloc2((size_t)N_NODES * HIDDEN * sizeof(__half));
    unsigned char* qbuf = (unsigned char*)alloc2((size_t)N_NODES * HIDDEN);
    __half* wt1     = (__half*)alloc2((size_t)N_LAYERS * HIDDEN * HIDDEN * sizeof(__half));
    __half* wt2     = (__half*)alloc2((size_t)N_LAYERS * HIDDEN * HIDDEN * sizeof(__half));
    int2*   wedge   = (int2*)alloc2((size_t)N_EDGES * sizeof(int2));
    int*    csr     = (int*)alloc2((size_t)N_EDGES * sizeof(int));
    int*    rowp    = (int*)alloc2((size_t)(N_NODES + 1) * sizeof(int));
    int*    counts  = (int*)alloc2((size_t)PLACE_BLOCKS * N_WIN * sizeof(int));
    int*    offsets = (int*)alloc2((size_t)PLACE_BLOCKS * N_WIN * sizeof(int));
    int*    colsum  = (int*)alloc2((size_t)N_WIN * sizeof(int));
    int*    gstart  = (int*)alloc2((size_t)(N_GRAPHS + 1) * sizeof(int));
    float*  pooled  = (float*)alloc2((size_t)N_GRAPHS * HIDDEN * N_LAYERS * sizeof(float));

    // CSR build: count -> column scan -> place -> fused per-window csr
    win_count_kernel<<<PLACE_BLOCKS, 256, 0, stream>>>(dst, counts);
    win_scan1_kernel<<<N_WIN, 128, 0, stream>>>(counts, offsets, colsum);
    win_place_kernel<<<PLACE_BLOCKS, 512, 0, stream>>>(src, dst, offsets, colsum, wedge);
    win_csr_kernel<<<N_WIN, 512, 0, stream>>>(wedge, colsum, rowp, csr);

    // fused prep: X conversions + weight transpose + graph-boundary search
    prep_kernel<<<PREP_BLOCKS, 256, 0, stream>>>(X, hA, qbuf, w1all, w2all, wt1, wt2,
                                                 batch, gstart);

    const int gat_grid = (N_NODES + 3) / 4;           // 25000

    __half* hcur = hA;
    for (int l = 0; l < N_LAYERS; ++l) {
        __half* hnext = (l & 1) ? hA : hB;
        const bool emit = (l < N_LAYERS - 1);
        if (l == 0) {
            gather_kernel<<<gat_grid, 256, 0, stream>>>(qbuf, hcur, zh, rowp, csr);
        } else {
            // gather(l) + gpool(l-1): both consume hcur (= mm2 output of l-1)
            gather_pool_kernel<<<gat_grid + POOL_BLKS, 256, 0, stream>>>(
                qbuf, hcur, zh, rowp, csr, gstart, pooled, l - 1);
        }
        mm_ws_kernel<<<MM_BLOCKS, 256, 0, stream>>>(zh,
                                                    wt1 + (size_t)l * HIDDEN * HIDDEN,
                                                    b1all + (size_t)l * HIDDEN,
                                                    m1h, (unsigned char*)nullptr);
        mm_ws_kernel<<<MM_BLOCKS, 256, 0, stream>>>(m1h,
                                                    wt2 + (size_t)l * HIDDEN * HIDDEN,
                                                    b2all + (size_t)l * HIDDEN,
                                                    hnext,
                                                    emit ? qbuf : (unsigned char*)nullptr);
        hcur = hnext;
    }

    gpool_kernel<<<N_GRAPHS, 256, 0, stream>>>(hcur, gstart, pooled, N_LAYERS - 1);
    cls_kernel<<<N_GRAPHS, 128, 0, stream>>>(pooled, cw1, cb1, cw2, cb2, cw3, cb3, out);
}

// Round 9
// 461.793 us; speedup vs baseline: 1.1319x; 1.0015x over previous
//
#include <hip/hip_runtime.h>
#include <hip/hip_fp16.h>
#include <cstddef>
#include <cstdint>

#define N_NODES   100000
#define N_EDGES   1600000
#define N_GRAPHS  512
#define HIDDEN    128
#define N_LAYERS  3

// 400-way counting sort (R9-confirmed). 128 place blocks (R13: ~31-edge runs
// per window -> near-full-line wedge writes).
#define N_WIN        400
#define WIN_NODES    (N_NODES / N_WIN)      // 250
#define PLACE_BLOCKS 128
#define PCHUNK       (N_EDGES / PLACE_BLOCKS)  // 12500, divisible by 4

#define F2H_BLOCKS   ((N_NODES * HIDDEN / 8) / 256)            // 6250
#define WCONV_BLOCKS (N_LAYERS * 2 * 16)                       // 96
#define GB_BLOCKS    2                                         // graph-boundary search
#define PREP_BLOCKS  (F2H_BLOCKS + WCONV_BLOCKS + GB_BLOCKS)

typedef _Float16 half8  __attribute__((ext_vector_type(8)));
typedef _Float16 half4v __attribute__((ext_vector_type(4)));
typedef _Float16 half2v __attribute__((ext_vector_type(2)));
typedef float    float8 __attribute__((ext_vector_type(8)));
typedef float    floatx4 __attribute__((ext_vector_type(4)));
typedef float    floatx2 __attribute__((ext_vector_type(2)));

// ---------------------------------------------------------------------------
__global__ __launch_bounds__(256) void win_count_kernel(const int* __restrict__ dst,
                                                        int* __restrict__ counts) {
    __shared__ int cs[N_WIN];
    for (int i = threadIdx.x; i < N_WIN; i += 256) cs[i] = 0;
    __syncthreads();
    const int4* d4 = (const int4*)(dst + blockIdx.x * PCHUNK);
    for (int i = threadIdx.x; i < PCHUNK / 4; i += 256) {
        int4 d = d4[i];
        atomicAdd(&cs[d.x / WIN_NODES], 1);
        atomicAdd(&cs[d.y / WIN_NODES], 1);
        atomicAdd(&cs[d.z / WIN_NODES], 1);
        atomicAdd(&cs[d.w / WIN_NODES], 1);
    }
    __syncthreads();
    for (int i = threadIdx.x; i < N_WIN; i += 256)
        counts[blockIdx.x * N_WIN + i] = cs[i];
}

// column scan over the 128 place-blocks; emits per-block offsets + col totals
__global__ __launch_bounds__(128) void win_scan1_kernel(const int* __restrict__ counts,
                                                        int* __restrict__ offsets,
                                                        int* __restrict__ colsum) {
    __shared__ int tmp[128];
    const int w = blockIdx.x;
    const int t = threadIdx.x;
    tmp[t] = counts[t * N_WIN + w];
    __syncthreads();
#pragma unroll
    for (int off = 1; off < 128; off <<= 1) {
        int u = (t >= off) ? tmp[t - off] : 0;
        __syncthreads();
        tmp[t] += u;
        __syncthreads();
    }
    offsets[t * N_WIN + w] = (t == 0) ? 0 : tmp[t - 1];
    if (t == 127) colsum[w] = tmp[127];
}

// place: re-derives winbase from colsum via in-LDS scan (win_scan2 removed)
__global__ __launch_bounds__(512) void win_place_kernel(const int* __restrict__ src,
                                                        const int* __restrict__ dst,
                                                        const int* __restrict__ offsets,
                                                        const int* __restrict__ colsum,
                                                        int2* __restrict__ wedge) {
    __shared__ int ws[512];
    __shared__ int off[N_WIN];
    const int t = threadIdx.x;
    ws[t] = (t < N_WIN) ? colsum[t] : 0;
    __syncthreads();
#pragma unroll
    for (int o = 1; o < 512; o <<= 1) {
        int u = (t >= o) ? ws[t - o] : 0;
        __syncthreads();
        ws[t] += u;
        __syncthreads();
    }
    if (t < N_WIN) off[t] = offsets[blockIdx.x * N_WIN + t] + ((t == 0) ? 0 : ws[t - 1]);
    __syncthreads();
    const int4* d4 = (const int4*)(dst + blockIdx.x * PCHUNK);
    const int4* s4 = (const int4*)(src + blockIdx.x * PCHUNK);
    for (int i = t; i < PCHUNK / 4; i += 512) {
        int4 d = d4[i];
        int4 s = s4[i];
        int p0 = atomicAdd(&off[d.x / WIN_NODES], 1); wedge[p0] = make_int2(d.x, s.x);
        int p1 = atomicAdd(&off[d.y / WIN_NODES], 1); wedge[p1] = make_int2(d.y, s.y);
        int p2 = atomicAdd(&off[d.z / WIN_NODES], 1); wedge[p2] = make_int2(d.z, s.z);
        int p3 = atomicAdd(&off[d.w / WIN_NODES], 1); wedge[p3] = make_int2(d.w, s.w);
    }
}

// fused per-window CSR: winbase scan -> count -> scan -> row_ptr -> scatter
__global__ __launch_bounds__(512) void win_csr_kernel(const int2* __restrict__ wedge,
                                                      const int* __restrict__ colsum,
                                                      int* __restrict__ row_ptr,
                                                      int* __restrict__ csr_src) {
    __shared__ int ws[512];
    __shared__ int cnt[WIN_NODES];
    __shared__ int bb[2];
    const int w = blockIdx.x, n0 = w * WIN_NODES, t = threadIdx.x;
    ws[t] = (t < N_WIN) ? colsum[t] : 0;
    __syncthreads();
#pragma unroll
    for (int o = 1; o < 512; o <<= 1) {
        int u = (t >= o) ? ws[t - o] : 0;
        __syncthreads();
        ws[t] += u;
        __syncthreads();
    }
    if (t == 0) { bb[0] = (w > 0) ? ws[w - 1] : 0; bb[1] = ws[w]; }
    if (w == N_WIN - 1 && t == 0) row_ptr[N_NODES] = ws[N_WIN - 1];
    for (int i = t; i < WIN_NODES; i += 512) cnt[i] = 0;
    __syncthreads();
    const int b0 = bb[0], b1 = bb[1];
    for (int e = b0 + t; e < b1; e += 512)
        atomicAdd(&cnt[wedge[e].x - n0], 1);
    __syncthreads();
    ws[t] = (t < WIN_NODES) ? cnt[t] : 0;
    __syncthreads();
#pragma unroll
    for (int o = 1; o < 512; o <<= 1) {
        int u = (t >= o) ? ws[t - o] : 0;
        __syncthreads();
        ws[t] += u;
        __syncthreads();
    }
    const int excl = (t == 0) ? 0 : ws[t - 1];
    if (t < WIN_NODES) {
        row_ptr[n0 + t] = b0 + excl;
        cnt[t] = b0 + excl;
    }
    __syncthreads();
    for (int e = b0 + t; e < b1; e += 512) {
        int2 ed = wedge[e];
        int p = atomicAdd(&cnt[ed.x - n0], 1);
        csr_src[p] = ed.y;
    }
}

// ---------------------------------------------------------------------------
// prep: grid-split fusion of (a) X fp32->fp16+fp8, (b) LDS-tiled weight
// transpose, (c) graph-boundary binary search.
// ---------------------------------------------------------------------------
__global__ __launch_bounds__(256) void prep_kernel(const float* __restrict__ X,
                                                   __half* __restrict__ hA,
                                                   unsigned char* __restrict__ outq,
                                                   const float* __restrict__ w1,
                                                   const float* __restrict__ w2,
                                                   __half* __restrict__ wt1,
                                                   __half* __restrict__ wt2,
                                                   const int* __restrict__ batch,
                                                   int* __restrict__ gstart) {
    __shared__ float tile[32][33];
    const int b = blockIdx.x;
    if (b < F2H_BLOCKS) {
        int t = b * 256 + threadIdx.x;
        const float4* in4 = (const float4*)X;
        float4 a = in4[t * 2 + 0];
        float4 c = in4[t * 2 + 1];
        __half2* o2 = (__half2*)hA;
        o2[t * 4 + 0] = __floats2half2_rn(a.x, a.y);
        o2[t * 4 + 1] = __floats2half2_rn(a.z, a.w);
        o2[t * 4 + 2] = __floats2half2_rn(c.x, c.y);
        o2[t * 4 + 3] = __floats2half2_rn(c.z, c.w);
        unsigned r0 = 0, r1 = 0;
        r0 = __builtin_amdgcn_cvt_pk_fp8_f32(a.x, a.y, r0, false);
        r0 = __builtin_amdgcn_cvt_pk_fp8_f32(a.z, a.w, r0, true);
        r1 = __builtin_amdgcn_cvt_pk_fp8_f32(c.x, c.y, r1, false);
        r1 = __builtin_amdgcn_cvt_pk_fp8_f32(c.z, c.w, r1, true);
        ((uint2*)outq)[t] = make_uint2(r0, r1);
    } else if (b < F2H_BLOCKS + WCONV_BLOCKS) {
        const int bb = b - F2H_BLOCKS;
        const int mat = bb & 1;
        const int tt = (bb >> 1) & 15;
        const int l  = bb >> 5;
        const int ti = (tt >> 2) * 32, tj = (tt & 3) * 32;
        const float* W = (mat ? w2 : w1) + (size_t)l * HIDDEN * HIDDEN;
        __half* WT = (mat ? wt2 : wt1) + (size_t)l * HIDDEN * HIDDEN;
        const int r = threadIdx.x >> 5;
        const int c = threadIdx.x & 31;
#pragma unroll
        for (int rr = 0; rr < 4; ++rr)
            tile[r + 8 * rr][c] = W[(size_t)(ti + r + 8 * rr) * HIDDEN + tj + c];
        __syncthreads();
#pragma unroll
        for (int rr = 0; rr < 4; ++rr)
            WT[(size_t)(tj + r + 8 * rr) * HIDDEN + ti + c] =
                __float2half(tile[c][r + 8 * rr]);
    } else {
        // graph-boundary search: gstart[g] = lower_bound(batch, g)
        const int g = (b - F2H_BLOCKS - WCONV_BLOCKS) * 256 + threadIdx.x;  // 0..511
        if (g < N_GRAPHS) {
            int lo = 0, hi = N_NODES;
            while (lo < hi) {
                int mid = (lo + hi) >> 1;
                if (batch[mid] < g) lo = mid + 1; else hi = mid;
            }
            gstart[g] = lo;
        }
        if (g == 0) gstart[N_GRAPHS] = N_NODES;
    }
}

// ---------------------------------------------------------------------------
// GIN aggregation, fp8 neighbors, packed-fp16 butterfly (R12/R13-confirmed).
// ---------------------------------------------------------------------------
__device__ __forceinline__ void acc_fp8x16(float* acc, uint4 v) {
    floatx2 f;
    f = __builtin_amdgcn_cvt_pk_f32_fp8(v.x, false); acc[0] += f.x;  acc[1] += f.y;
    f = __builtin_amdgcn_cvt_pk_f32_fp8(v.x, true);  acc[2] += f.x;  acc[3] += f.y;
    f = __builtin_amdgcn_cvt_pk_f32_fp8(v.y, false); acc[4] += f.x;  acc[5] += f.y;
    f = __builtin_amdgcn_cvt_pk_f32_fp8(v.y, true);  acc[6] += f.x;  acc[7] += f.y;
    f = __builtin_amdgcn_cvt_pk_f32_fp8(v.z, false); acc[8] += f.x;  acc[9] += f.y;
    f = __builtin_amdgcn_cvt_pk_f32_fp8(v.z, true);  acc[10] += f.x; acc[11] += f.y;
    f = __builtin_amdgcn_cvt_pk_f32_fp8(v.w, false); acc[12] += f.x; acc[13] += f.y;
    f = __builtin_amdgcn_cvt_pk_f32_fp8(v.w, true);  acc[14] += f.x; acc[15] += f.y;
}

__device__ __forceinline__ void gather_body(int wave, int lane,
                                            const unsigned char* __restrict__ Xq,
                                            const __half* __restrict__ Xh,
                                            __half* __restrict__ Zh,
                                            const int* __restrict__ row_ptr,
                                            const int* __restrict__ csr_src) {
    const int grp = lane >> 3;     // 0..7
    const int m   = lane & 7;      // 0..7
    const uint4* Q = (const uint4*)Xq;   // row = 8 x uint4 (128B)

    float acc[16];
#pragma unroll
    for (int j = 0; j < 16; ++j) acc[j] = 0.f;

    int k = row_ptr[wave];
    const int end = row_ptr[wave + 1];

    for (; k + 16 <= end; k += 16) {
        int n0 = csr_src[k + grp];
        int n1 = csr_src[k + 8 + grp];
        uint4 v0 = Q[(size_t)n0 * 8 + m];
        uint4 v1 = Q[(size_t)n1 * 8 + m];
        acc_fp8x16(acc, v0);
        acc_fp8x16(acc, v1);
    }
    if (k + 8 <= end) {
        int n0 = csr_src[k + grp];
        uint4 v0 = Q[(size_t)n0 * 8 + m];
        acc_fp8x16(acc, v0);
        k += 8;
    }
    int rem = end - k;
    if (grp < rem) {
        int n0 = csr_src[k + grp];
        uint4 v0 = Q[(size_t)n0 * 8 + m];
        acc_fp8x16(acc, v0);
    }

    half2v hh[8];
#pragma unroll
    for (int j = 0; j < 8; ++j) {
        hh[j][0] = (_Float16)acc[2 * j];
        hh[j][1] = (_Float16)acc[2 * j + 1];
    }
#pragma unroll
    for (int j = 0; j < 8; ++j) {
        int b = __shfl_xor(__builtin_bit_cast(int, hh[j]), 8);
        hh[j] = hh[j] + __builtin_bit_cast(half2v, b);
    }
#pragma unroll
    for (int j = 0; j < 8; ++j) {
        int b = __shfl_xor(__builtin_bit_cast(int, hh[j]), 16);
        hh[j] = hh[j] + __builtin_bit_cast(half2v, b);
    }
#pragma unroll
    for (int j = 0; j < 8; ++j) {
        int b = __shfl_xor(__builtin_bit_cast(int, hh[j]), 32);
        hh[j] = hh[j] + __builtin_bit_cast(half2v, b);
    }

    if (grp == 0) {
        const half2v* H2 = (const half2v*)(Xh + (size_t)wave * HIDDEN + 16 * m);
        half8 o0, o1;
#pragma unroll
        for (int j = 0; j < 4; ++j) {
            half2v s = hh[j] + H2[j];
            o0[2 * j] = s[0]; o0[2 * j + 1] = s[1];
        }
#pragma unroll
        for (int j = 0; j < 4; ++j) {
            half2v s = hh[4 + j] + H2[4 + j];
            o1[2 * j] = s[0]; o1[2 * j + 1] = s[1];
        }
        ((half8*)(Zh + (size_t)wave * HIDDEN + 16 * m))[0] = o0;
        ((half8*)(Zh + (size_t)wave * HIDDEN + 16 * m))[1] = o1;
    }
}

__global__ void gather_kernel(const unsigned char* __restrict__ Xq,
                              const __half* __restrict__ Xh,
                              __half* __restrict__ Zh,
                              const int* __restrict__ row_ptr,
                              const int* __restrict__ csr_src) {
    int wave = (blockIdx.x * blockDim.x + threadIdx.x) >> 6;
    if (wave >= N_NODES) return;
    gather_body(wave, threadIdx.x & 63, Xq, Xh, Zh, row_ptr, csr_src);
}

// ---------------------------------------------------------------------------
// Atomic-free global pooling (R15-confirmed). One block per graph.
// ---------------------------------------------------------------------------
__device__ __forceinline__ void gpool_body(int g,
                                           const __half* __restrict__ Xh,
                                           const int* __restrict__ gstart,
                                           float* __restrict__ pooled, int layer) {
    __shared__ float red[16][16][8];   // 8 KiB
    const int f8 = threadIdx.x & 15;   // col group: cols f8*8 .. f8*8+7
    const int qt = threadIdx.x >> 4;   // row phase 0..15
    const int s = gstart[g], e = gstart[g + 1];

    float acc[8];
#pragma unroll
    for (int j = 0; j < 8; ++j) acc[j] = 0.f;

    for (int n = s + qt; n < e; n += 16) {
        half8 v = ((const half8*)(Xh + (size_t)n * HIDDEN))[f8];
#pragma unroll
        for (int j = 0; j < 8; ++j) acc[j] += (float)v[j];
    }
#pragma unroll
    for (int j = 0; j < 8; ++j) red[qt][f8][j] = acc[j];
    __syncthreads();

    if (threadIdx.x < 128) {
        const int c = threadIdx.x;
        float sum = 0.f;
#pragma unroll
        for (int p = 0; p < 16; ++p) sum += red[p][c >> 3][c & 7];
        pooled[(size_t)g * (HIDDEN * N_LAYERS) + layer * HIDDEN + c] = sum;
    }
}

__global__ __launch_bounds__(256) void gpool_kernel(const __half* __restrict__ Xh,
                                                    const int* __restrict__ gstart,
                                                    float* __restrict__ pooled,
                                                    int layer) {
    gpool_body(blockIdx.x, Xh, gstart, pooled, layer);
}

// gather(l) + gpool(l-1) grid-split fusion (R16-confirmed): both consume the
// same mm2 output; pool blocks FIRST so their streaming rides under gather's
// latency-bound phase.
#define POOL_BLKS N_GRAPHS   // 512
__global__ __launch_bounds__(256) void gather_pool_kernel(const unsigned char* __restrict__ Xq,
                                                          const __half* __restrict__ Xh,
                                                          __half* __restrict__ Zh,
                                                          const int* __restrict__ row_ptr,
                                                          const int* __restrict__ csr_src,
                                                          const int* __restrict__ gstart,
                                                          float* __restrict__ pooled,
                                                          int prev_layer) {
    if (blockIdx.x < POOL_BLKS) {
        gpool_body(blockIdx.x, Xh, gstart, pooled, prev_layer);
        return;
    }
    int wave = ((blockIdx.x - POOL_BLKS) * 256 + threadIdx.x) >> 6;
    if (wave >= N_NODES) return;
    gather_body(wave, threadIdx.x & 63, Xq, Xh, Zh, row_ptr, csr_src);
}

// ---------------------------------------------------------------------------
// Fused wave-split MLP (R21 = R20 with the __half/_Float16 type fix): mm1+mm2
// in one kernel, 8 waves x 512 threads. Wave wv owns output cols
// [wv*16, wv*16+16) for BOTH matmuls -> weight fragments = 16+16 VGPRs
// (R7-proven no-spill regime; R5/R6 showed full-panel-per-wave designs spill
// ~150 MB phantom HBM traffic). h handoff mm1->mm2 via double-buffered 8 KB
// LDS tile with the R5-proven XOR-chunk swizzle (2-way bank alias = free):
//   write: lane(m,q) puts cols wv*16+q*4..+3 at chunk (2wv+(q>>1))^m,
//          half-chunk (q&1).
//   read:  lane(m,q) frag c = chunk (c*4+q)^m of row m.
// ONE barrier per tile; dbuf makes the next write race-free (a wave reaches
// the hs[b] overwrite in iter k+2 only after the k+1 barrier, which all waves
// pass only after their iter-k reads). No atomics. No prefetch (keeps VGPR
// ~90, far from the 128 cliff).
// ---------------------------------------------------------------------------
#define MMF_BLOCKS 2048
__global__ __launch_bounds__(512) void mlp_ws_kernel(const __half* __restrict__ A,
                                                     const __half* __restrict__ Wt1,
                                                     const __half* __restrict__ Wt2,
                                                     const float* __restrict__ b1,
                                                     const float* __restrict__ b2,
                                                     __half* __restrict__ C16,
                                                     unsigned char* __restrict__ Q8) {
    __shared__ _Float16 hs[2][16][128];   // 8 KiB, XOR-swizzled 16B chunks

    const int tid  = threadIdx.x;
    const int wv   = tid >> 6;         // 0..7: owned ct (16 output cols)
    const int lane = tid & 63;
    const int m    = lane & 15;
    const int q    = lane >> 4;
    const int NTILES = N_NODES / 16;   // 6250

    // per-wave weight slices + biases (register-resident, 40 VGPRs)
    half8 wf1[4], wf2[4];
    float bl1[4], bl2[4];
    {
        const half8* W1row = (const half8*)(Wt1 + (size_t)(wv * 16 + m) * HIDDEN);
        const half8* W2row = (const half8*)(Wt2 + (size_t)(wv * 16 + m) * HIDDEN);
#pragma unroll
        for (int c = 0; c < 4; ++c) { wf1[c] = W1row[c * 4 + q]; wf2[c] = W2row[c * 4 + q]; }
#pragma unroll
        for (int r = 0; r < 4; ++r) {
            bl1[r] = b1[wv * 16 + q * 4 + r];
            bl2[r] = b2[wv * 16 + q * 4 + r];
        }
    }

    // h-store address (swizzled): chunk (2wv + (q>>1)) ^ m, half-chunk q&1
    _Float16* hwr0 = &hs[0][m][(((2 * wv + (q >> 1)) ^ m) << 3) + ((q & 1) << 2)];
    _Float16* hwr1 = &hs[1][m][(((2 * wv + (q >> 1)) ^ m) << 3) + ((q & 1) << 2)];
    const _Float16* hrd0 = &hs[0][m][0];
    const _Float16* hrd1 = &hs[1][m][0];

    int buf = 0;
    for (int t = blockIdx.x; t < NTILES; t += MMF_BLOCKS) {
        // ---- load A tile (all 8 waves read the same 4 KB; L1 serves 2..8)
        const half8* Arow = (const half8*)(A + (size_t)(t * 16 + m) * HIDDEN);
        half8 a0 = Arow[q];
        half8 a1 = Arow[4 + q];
        half8 a2 = Arow[8 + q];
        half8 a3 = Arow[12 + q];

        // ---- mm1: h(:, wv-slice) = relu(z @ W1 + b1) -> swizzled LDS
        {
            floatx4 acc = {0.f, 0.f, 0.f, 0.f};
            acc = __builtin_amdgcn_mfma_f32_16x16x32_f16(wf1[0], a0, acc, 0, 0, 0);
            acc = __builtin_amdgcn_mfma_f32_16x16x32_f16(wf1[1], a1, acc, 0, 0, 0);
            acc = __builtin_amdgcn_mfma_f32_16x16x32_f16(wf1[2], a2, acc, 0, 0, 0);
            acc = __builtin_amdgcn_mfma_f32_16x16x32_f16(wf1[3], a3, acc, 0, 0, 0);
            half4v o;
#pragma unroll
            for (int r = 0; r < 4; ++r) o[r] = (_Float16)fmaxf(acc[r] + bl1[r], 0.f);
            *(half4v*)(buf ? hwr1 : hwr0) = o;
        }
        __syncthreads();

        // ---- mm2: read full h row fragments (swizzled), compute wv-slice
        {
            const _Float16* hr = buf ? hrd1 : hrd0;
            half8 h0 = *(const half8*)(hr + (((0 + q) ^ m) << 3));
            half8 h1 = *(const half8*)(hr + (((4 + q) ^ m) << 3));
            half8 h2 = *(const half8*)(hr + (((8 + q) ^ m) << 3));
            half8 h3 = *(const half8*)(hr + (((12 + q) ^ m) << 3));
            floatx4 acc = {0.f, 0.f, 0.f, 0.f};
            acc = __builtin_amdgcn_mfma_f32_16x16x32_f16(wf2[0], h0, acc, 0, 0, 0);
            acc = __builtin_amdgcn_mfma_f32_16x16x32_f16(wf2[1], h1, acc, 0, 0, 0);
            acc = __builtin_amdgcn_mfma_f32_16x16x32_f16(wf2[2], h2, acc, 0, 0, 0);
            acc = __builtin_amdgcn_mfma_f32_16x16x32_f16(wf2[3], h3, acc, 0, 0, 0);
            float v0 = fmaxf(acc[0] + bl2[0], 0.f);
            float v1 = fmaxf(acc[1] + bl2[1], 0.f);
            float v2 = fmaxf(acc[2] + bl2[2], 0.f);
            float v3 = fmaxf(acc[3] + bl2[3], 0.f);
            const size_t base = (size_t)(t * 16 + m) * HIDDEN + wv * 16 + q * 4;
            half4v o;
            o[0] = (_Float16)v0; o[1] = (_Float16)v1;
            o[2] = (_Float16)v2; o[3] = (_Float16)v3;
            *(half4v*)(C16 + base) = o;
            if (Q8) {
                unsigned r0 = 0;
                r0 = __builtin_amdgcn_cvt_pk_fp8_f32(v0, v1, r0, false);
                r0 = __builtin_amdgcn_cvt_pk_fp8_f32(v2, v3, r0, true);
                *(unsigned*)(Q8 + base) = r0;
            }
        }
        buf ^= 1;
    }
}

// ---------------------------------------------------------------------------
__global__ __launch_bounds__(128) void cls_kernel(const float* __restrict__ pooled,
                                                  const float* __restrict__ w1,
                                                  const float* __restrict__ b1,
                                                  const float* __restrict__ w2,
                                                  const float* __restrict__ b2,
                                                  const float* __restrict__ w3,
                                                  const float* __restrict__ b3,
                                                  float* __restrict__ out) {
    __shared__ float hin[HIDDEN * N_LAYERS];
    __shared__ float h1[HIDDEN];
    __shared__ float red[HIDDEN];
    const int g = blockIdx.x;
    const int t = threadIdx.x;

    for (int i = t; i < HIDDEN * N_LAYERS; i += 128)
        hin[i] = pooled[(size_t)g * (HIDDEN * N_LAYERS) + i];
    __syncthreads();

    float s = 0.f;
    for (int k = 0; k < HIDDEN * N_LAYERS; ++k) s += hin[k] * w1[(size_t)k * HIDDEN + t];
    s = fmaxf(s + b1[t], 0.f);
    h1[t] = s;
    __syncthreads();

    float s2 = 0.f;
    for (int k = 0; k < HIDDEN; ++k) s2 += h1[k] * w2[(size_t)k * HIDDEN + t];
    s2 = fmaxf(s2 + b2[t], 0.f);

    red[t] = s2 * w3[t];
    __syncthreads();
    for (int off = 64; off > 0; off >>= 1) {
        if (t < off) red[t] += red[t + off];
        __syncthreads();
    }
    if (t == 0) out[g] = red[0] + b3[0];
}

// ---------------------------------------------------------------------------
extern "C" void kernel_launch(void* const* d_in, const int* in_sizes, int n_in,
                              void* d_out, int out_size, void* d_ws, size_t ws_size,
                              hipStream_t stream) {
    const float* X     = (const float*)d_in[0];
    const int*   ei    = (const int*)d_in[1];
    const int*   batch = (const int*)d_in[2];
    const float* w1all = (const float*)d_in[3];
    const float* b1all = (const float*)d_in[4];
    const float* w2all = (const float*)d_in[5];
    const float* b2all = (const float*)d_in[6];
    const float* cw1   = (const float*)d_in[7];
    const float* cb1   = (const float*)d_in[8];
    const float* cw2   = (const float*)d_in[9];
    const float* cb2   = (const float*)d_in[10];
    const float* cw3   = (const float*)d_in[11];
    const float* cb3   = (const float*)d_in[12];
    float* out = (float*)d_out;

    const int* src = ei;
    const int* dst = ei + N_EDGES;

    char* p = (char*)d_ws;
    auto alloc2 = [&](size_t bytes) {
        char* r = p;
        p += (bytes + 255) & ~(size_t)255;
        return r;
    };
    __half* hA      = (__half*)alloc2((size_t)N_NODES * HIDDEN * sizeof(__half));
    __half* hB      = (__half*)alloc2((size_t)N_NODES * HIDDEN * sizeof(__half));
    __half* zh      = (__half*)alloc2((size_t)N_NODES * HIDDEN * sizeof(__half));
    unsigned char* qbuf = (unsigned char*)alloc2((size_t)N_NODES * HIDDEN);
    __half* wt1     = (__half*)alloc2((size_t)N_LAYERS * HIDDEN * HIDDEN * sizeof(__half));
    __half* wt2     = (__half*)alloc2((size_t)N_LAYERS * HIDDEN * HIDDEN * sizeof(__half));
    int2*   wedge   = (int2*)alloc2((size_t)N_EDGES * sizeof(int2));
    int*    csr     = (int*)alloc2((size_t)N_EDGES * sizeof(int));
    int*    rowp    = (int*)alloc2((size_t)(N_NODES + 1) * sizeof(int));
    int*    counts  = (int*)alloc2((size_t)PLACE_BLOCKS * N_WIN * sizeof(int));
    int*    offsets = (int*)alloc2((size_t)PLACE_BLOCKS * N_WIN * sizeof(int));
    int*    colsum  = (int*)alloc2((size_t)N_WIN * sizeof(int));
    int*    gstart  = (int*)alloc2((size_t)(N_GRAPHS + 1) * sizeof(int));
    float*  pooled  = (float*)alloc2((size_t)N_GRAPHS * HIDDEN * N_LAYERS * sizeof(float));

    // CSR build: count -> column scan -> place -> fused per-window csr
    win_count_kernel<<<PLACE_BLOCKS, 256, 0, stream>>>(dst, counts);
    win_scan1_kernel<<<N_WIN, 128, 0, stream>>>(counts, offsets, colsum);
    win_place_kernel<<<PLACE_BLOCKS, 512, 0, stream>>>(src, dst, offsets, colsum, wedge);
    win_csr_kernel<<<N_WIN, 512, 0, stream>>>(wedge, colsum, rowp, csr);

    // fused prep: X conversions + weight transpose + graph-boundary search
    prep_kernel<<<PREP_BLOCKS, 256, 0, stream>>>(X, hA, qbuf, w1all, w2all, wt1, wt2,
                                                 batch, gstart);

    const int gat_grid = (N_NODES + 3) / 4;           // 25000

    __half* hcur = hA;
    for (int l = 0; l < N_LAYERS; ++l) {
        __half* hnext = (l & 1) ? hA : hB;
        const bool emit = (l < N_LAYERS - 1);
        if (l == 0) {
            gather_kernel<<<gat_grid, 256, 0, stream>>>(qbuf, hcur, zh, rowp, csr);
        } else {
            // gather(l) + gpool(l-1): both consume hcur (= mm2 output of l-1)
            gather_pool_kernel<<<gat_grid + POOL_BLKS, 256, 0, stream>>>(
                qbuf, hcur, zh, rowp, csr, gstart, pooled, l - 1);
        }
        mlp_ws_kernel<<<MMF_BLOCKS, 512, 0, stream>>>(zh,
                                                      wt1 + (size_t)l * HIDDEN * HIDDEN,
                                                      wt2 + (size_t)l * HIDDEN * HIDDEN,
                                                      b1all + (size_t)l * HIDDEN,
                                                      b2all + (size_t)l * HIDDEN,
                                                      hnext,
                                                      emit ? qbuf : (unsigned char*)nullptr);
        hcur = hnext;
    }

    gpool_kernel<<<N_GRAPHS, 256, 0, stream>>>(hcur, gstart, pooled, N_LAYERS - 1);
    cls_kernel<<<N_GRAPHS, 128, 0, stream>>>(pooled, cw1, cb1, cw2, cb2, cw3, cb3, out);
}

// Round 10
// 426.061 us; speedup vs baseline: 1.2268x; 1.0839x over previous
//
#include <hip/hip_runtime.h>
#include <hip/hip_fp16.h>
#include <cstddef>
#include <cstdint>

#define N_NODES   100000
#define N_EDGES   1600000
#define N_GRAPHS  512
#define HIDDEN    128
#define N_LAYERS  3

// 400-way counting sort (R9-confirmed). 128 place blocks (R13: ~31-edge runs
// per window -> near-full-line wedge writes).
#define N_WIN        400
#define WIN_NODES    (N_NODES / N_WIN)      // 250
#define PLACE_BLOCKS 128
#define PCHUNK       (N_EDGES / PLACE_BLOCKS)  // 12500, divisible by 4

#define F2H_BLOCKS   ((N_NODES * HIDDEN / 8) / 256)            // 6250
#define WCONV_BLOCKS (N_LAYERS * 2 * 16)                       // 96
#define GB_BLOCKS    2                                         // graph-boundary search
#define PREP_BLOCKS  (F2H_BLOCKS + WCONV_BLOCKS + GB_BLOCKS)

typedef _Float16 half8  __attribute__((ext_vector_type(8)));
typedef _Float16 half4v __attribute__((ext_vector_type(4)));
typedef _Float16 half2v __attribute__((ext_vector_type(2)));
typedef float    float8 __attribute__((ext_vector_type(8)));
typedef float    floatx4 __attribute__((ext_vector_type(4)));
typedef float    floatx2 __attribute__((ext_vector_type(2)));

// ---------------------------------------------------------------------------
__global__ __launch_bounds__(256) void win_count_kernel(const int* __restrict__ dst,
                                                        int* __restrict__ counts) {
    __shared__ int cs[N_WIN];
    for (int i = threadIdx.x; i < N_WIN; i += 256) cs[i] = 0;
    __syncthreads();
    const int4* d4 = (const int4*)(dst + blockIdx.x * PCHUNK);
    for (int i = threadIdx.x; i < PCHUNK / 4; i += 256) {
        int4 d = d4[i];
        atomicAdd(&cs[d.x / WIN_NODES], 1);
        atomicAdd(&cs[d.y / WIN_NODES], 1);
        atomicAdd(&cs[d.z / WIN_NODES], 1);
        atomicAdd(&cs[d.w / WIN_NODES], 1);
    }
    __syncthreads();
    for (int i = threadIdx.x; i < N_WIN; i += 256)
        counts[blockIdx.x * N_WIN + i] = cs[i];
}

// column scan over the 128 place-blocks; emits per-block offsets + col totals
__global__ __launch_bounds__(128) void win_scan1_kernel(const int* __restrict__ counts,
                                                        int* __restrict__ offsets,
                                                        int* __restrict__ colsum) {
    __shared__ int tmp[128];
    const int w = blockIdx.x;
    const int t = threadIdx.x;
    tmp[t] = counts[t * N_WIN + w];
    __syncthreads();
#pragma unroll
    for (int off = 1; off < 128; off <<= 1) {
        int u = (t >= off) ? tmp[t - off] : 0;
        __syncthreads();
        tmp[t] += u;
        __syncthreads();
    }
    offsets[t * N_WIN + w] = (t == 0) ? 0 : tmp[t - 1];
    if (t == 127) colsum[w] = tmp[127];
}

// place: re-derives winbase from colsum via in-LDS scan (win_scan2 removed)
__global__ __launch_bounds__(512) void win_place_kernel(const int* __restrict__ src,
                                                        const int* __restrict__ dst,
                                                        const int* __restrict__ offsets,
                                                        const int* __restrict__ colsum,
                                                        int2* __restrict__ wedge) {
    __shared__ int ws[512];
    __shared__ int off[N_WIN];
    const int t = threadIdx.x;
    ws[t] = (t < N_WIN) ? colsum[t] : 0;
    __syncthreads();
#pragma unroll
    for (int o = 1; o < 512; o <<= 1) {
        int u = (t >= o) ? ws[t - o] : 0;
        __syncthreads();
        ws[t] += u;
        __syncthreads();
    }
    if (t < N_WIN) off[t] = offsets[blockIdx.x * N_WIN + t] + ((t == 0) ? 0 : ws[t - 1]);
    __syncthreads();
    const int4* d4 = (const int4*)(dst + blockIdx.x * PCHUNK);
    const int4* s4 = (const int4*)(src + blockIdx.x * PCHUNK);
    for (int i = t; i < PCHUNK / 4; i += 512) {
        int4 d = d4[i];
        int4 s = s4[i];
        int p0 = atomicAdd(&off[d.x / WIN_NODES], 1); wedge[p0] = make_int2(d.x, s.x);
        int p1 = atomicAdd(&off[d.y / WIN_NODES], 1); wedge[p1] = make_int2(d.y, s.y);
        int p2 = atomicAdd(&off[d.z / WIN_NODES], 1); wedge[p2] = make_int2(d.z, s.z);
        int p3 = atomicAdd(&off[d.w / WIN_NODES], 1); wedge[p3] = make_int2(d.w, s.w);
    }
}

// fused per-window CSR: winbase scan -> count -> scan -> row_ptr -> scatter
__global__ __launch_bounds__(512) void win_csr_kernel(const int2* __restrict__ wedge,
                                                      const int* __restrict__ colsum,
                                                      int* __restrict__ row_ptr,
                                                      int* __restrict__ csr_src) {
    __shared__ int ws[512];
    __shared__ int cnt[WIN_NODES];
    __shared__ int bb[2];
    const int w = blockIdx.x, n0 = w * WIN_NODES, t = threadIdx.x;
    ws[t] = (t < N_WIN) ? colsum[t] : 0;
    __syncthreads();
#pragma unroll
    for (int o = 1; o < 512; o <<= 1) {
        int u = (t >= o) ? ws[t - o] : 0;
        __syncthreads();
        ws[t] += u;
        __syncthreads();
    }
    if (t == 0) { bb[0] = (w > 0) ? ws[w - 1] : 0; bb[1] = ws[w]; }
    if (w == N_WIN - 1 && t == 0) row_ptr[N_NODES] = ws[N_WIN - 1];
    for (int i = t; i < WIN_NODES; i += 512) cnt[i] = 0;
    __syncthreads();
    const int b0 = bb[0], b1 = bb[1];
    for (int e = b0 + t; e < b1; e += 512)
        atomicAdd(&cnt[wedge[e].x - n0], 1);
    __syncthreads();
    ws[t] = (t < WIN_NODES) ? cnt[t] : 0;
    __syncthreads();
#pragma unroll
    for (int o = 1; o < 512; o <<= 1) {
        int u = (t >= o) ? ws[t - o] : 0;
        __syncthreads();
        ws[t] += u;
        __syncthreads();
    }
    const int excl = (t == 0) ? 0 : ws[t - 1];
    if (t < WIN_NODES) {
        row_ptr[n0 + t] = b0 + excl;
        cnt[t] = b0 + excl;
    }
    __syncthreads();
    for (int e = b0 + t; e < b1; e += 512) {
        int2 ed = wedge[e];
        int p = atomicAdd(&cnt[ed.x - n0], 1);
        csr_src[p] = ed.y;
    }
}

// ---------------------------------------------------------------------------
// prep: grid-split fusion of (a) X fp32->fp16+fp8, (b) LDS-tiled weight
// transpose, (c) graph-boundary binary search.
// ---------------------------------------------------------------------------
__global__ __launch_bounds__(256) void prep_kernel(const float* __restrict__ X,
                                                   __half* __restrict__ hA,
                                                   unsigned char* __restrict__ outq,
                                                   const float* __restrict__ w1,
                                                   const float* __restrict__ w2,
                                                   __half* __restrict__ wt1,
                                                   __half* __restrict__ wt2,
                                                   const int* __restrict__ batch,
                                                   int* __restrict__ gstart) {
    __shared__ float tile[32][33];
    const int b = blockIdx.x;
    if (b < F2H_BLOCKS) {
        int t = b * 256 + threadIdx.x;
        const float4* in4 = (const float4*)X;
        float4 a = in4[t * 2 + 0];
        float4 c = in4[t * 2 + 1];
        __half2* o2 = (__half2*)hA;
        o2[t * 4 + 0] = __floats2half2_rn(a.x, a.y);
        o2[t * 4 + 1] = __floats2half2_rn(a.z, a.w);
        o2[t * 4 + 2] = __floats2half2_rn(c.x, c.y);
        o2[t * 4 + 3] = __floats2half2_rn(c.z, c.w);
        unsigned r0 = 0, r1 = 0;
        r0 = __builtin_amdgcn_cvt_pk_fp8_f32(a.x, a.y, r0, false);
        r0 = __builtin_amdgcn_cvt_pk_fp8_f32(a.z, a.w, r0, true);
        r1 = __builtin_amdgcn_cvt_pk_fp8_f32(c.x, c.y, r1, false);
        r1 = __builtin_amdgcn_cvt_pk_fp8_f32(c.z, c.w, r1, true);
        ((uint2*)outq)[t] = make_uint2(r0, r1);
    } else if (b < F2H_BLOCKS + WCONV_BLOCKS) {
        const int bb = b - F2H_BLOCKS;
        const int mat = bb & 1;
        const int tt = (bb >> 1) & 15;
        const int l  = bb >> 5;
        const int ti = (tt >> 2) * 32, tj = (tt & 3) * 32;
        const float* W = (mat ? w2 : w1) + (size_t)l * HIDDEN * HIDDEN;
        __half* WT = (mat ? wt2 : wt1) + (size_t)l * HIDDEN * HIDDEN;
        const int r = threadIdx.x >> 5;
        const int c = threadIdx.x & 31;
#pragma unroll
        for (int rr = 0; rr < 4; ++rr)
            tile[r + 8 * rr][c] = W[(size_t)(ti + r + 8 * rr) * HIDDEN + tj + c];
        __syncthreads();
#pragma unroll
        for (int rr = 0; rr < 4; ++rr)
            WT[(size_t)(tj + r + 8 * rr) * HIDDEN + ti + c] =
                __float2half(tile[c][r + 8 * rr]);
    } else {
        // graph-boundary search: gstart[g] = lower_bound(batch, g)
        const int g = (b - F2H_BLOCKS - WCONV_BLOCKS) * 256 + threadIdx.x;  // 0..511
        if (g < N_GRAPHS) {
            int lo = 0, hi = N_NODES;
            while (lo < hi) {
                int mid = (lo + hi) >> 1;
                if (batch[mid] < g) lo = mid + 1; else hi = mid;
            }
            gstart[g] = lo;
        }
        if (g == 0) gstart[N_GRAPHS] = N_NODES;
    }
}

// ---------------------------------------------------------------------------
// GIN aggregation, fp8 neighbors, packed-fp16 butterfly (R12/R13-confirmed).
// ---------------------------------------------------------------------------
__device__ __forceinline__ void acc_fp8x16(float* acc, uint4 v) {
    floatx2 f;
    f = __builtin_amdgcn_cvt_pk_f32_fp8(v.x, false); acc[0] += f.x;  acc[1] += f.y;
    f = __builtin_amdgcn_cvt_pk_f32_fp8(v.x, true);  acc[2] += f.x;  acc[3] += f.y;
    f = __builtin_amdgcn_cvt_pk_f32_fp8(v.y, false); acc[4] += f.x;  acc[5] += f.y;
    f = __builtin_amdgcn_cvt_pk_f32_fp8(v.y, true);  acc[6] += f.x;  acc[7] += f.y;
    f = __builtin_amdgcn_cvt_pk_f32_fp8(v.z, false); acc[8] += f.x;  acc[9] += f.y;
    f = __builtin_amdgcn_cvt_pk_f32_fp8(v.z, true);  acc[10] += f.x; acc[11] += f.y;
    f = __builtin_amdgcn_cvt_pk_f32_fp8(v.w, false); acc[12] += f.x; acc[13] += f.y;
    f = __builtin_amdgcn_cvt_pk_f32_fp8(v.w, true);  acc[14] += f.x; acc[15] += f.y;
}

__device__ __forceinline__ void gather_body(int wave, int lane,
                                            const unsigned char* __restrict__ Xq,
                                            const __half* __restrict__ Xh,
                                            __half* __restrict__ Zh,
                                            const int* __restrict__ row_ptr,
                                            const int* __restrict__ csr_src) {
    const int grp = lane >> 3;     // 0..7
    const int m   = lane & 7;      // 0..7
    const uint4* Q = (const uint4*)Xq;   // row = 8 x uint4 (128B)

    float acc[16];
#pragma unroll
    for (int j = 0; j < 16; ++j) acc[j] = 0.f;

    int k = row_ptr[wave];
    const int end = row_ptr[wave + 1];

    for (; k + 16 <= end; k += 16) {
        int n0 = csr_src[k + grp];
        int n1 = csr_src[k + 8 + grp];
        uint4 v0 = Q[(size_t)n0 * 8 + m];
        uint4 v1 = Q[(size_t)n1 * 8 + m];
        acc_fp8x16(acc, v0);
        acc_fp8x16(acc, v1);
    }
    if (k + 8 <= end) {
        int n0 = csr_src[k + grp];
        uint4 v0 = Q[(size_t)n0 * 8 + m];
        acc_fp8x16(acc, v0);
        k += 8;
    }
    int rem = end - k;
    if (grp < rem) {
        int n0 = csr_src[k + grp];
        uint4 v0 = Q[(size_t)n0 * 8 + m];
        acc_fp8x16(acc, v0);
    }

    half2v hh[8];
#pragma unroll
    for (int j = 0; j < 8; ++j) {
        hh[j][0] = (_Float16)acc[2 * j];
        hh[j][1] = (_Float16)acc[2 * j + 1];
    }
#pragma unroll
    for (int j = 0; j < 8; ++j) {
        int b = __shfl_xor(__builtin_bit_cast(int, hh[j]), 8);
        hh[j] = hh[j] + __builtin_bit_cast(half2v, b);
    }
#pragma unroll
    for (int j = 0; j < 8; ++j) {
        int b = __shfl_xor(__builtin_bit_cast(int, hh[j]), 16);
        hh[j] = hh[j] + __builtin_bit_cast(half2v, b);
    }
#pragma unroll
    for (int j = 0; j < 8; ++j) {
        int b = __shfl_xor(__builtin_bit_cast(int, hh[j]), 32);
        hh[j] = hh[j] + __builtin_bit_cast(half2v, b);
    }

    if (grp == 0) {
        const half2v* H2 = (const half2v*)(Xh + (size_t)wave * HIDDEN + 16 * m);
        half8 o0, o1;
#pragma unroll
        for (int j = 0; j < 4; ++j) {
            half2v s = hh[j] + H2[j];
            o0[2 * j] = s[0]; o0[2 * j + 1] = s[1];
        }
#pragma unroll
        for (int j = 0; j < 4; ++j) {
            half2v s = hh[4 + j] + H2[4 + j];
            o1[2 * j] = s[0]; o1[2 * j + 1] = s[1];
        }
        ((half8*)(Zh + (size_t)wave * HIDDEN + 16 * m))[0] = o0;
        ((half8*)(Zh + (size_t)wave * HIDDEN + 16 * m))[1] = o1;
    }
}

__global__ void gather_kernel(const unsigned char* __restrict__ Xq,
                              const __half* __restrict__ Xh,
                              __half* __restrict__ Zh,
                              const int* __restrict__ row_ptr,
                              const int* __restrict__ csr_src) {
    int wave = (blockIdx.x * blockDim.x + threadIdx.x) >> 6;
    if (wave >= N_NODES) return;
    gather_body(wave, threadIdx.x & 63, Xq, Xh, Zh, row_ptr, csr_src);
}

// ---------------------------------------------------------------------------
// Atomic-free global pooling (R15-confirmed). One block per graph.
// ---------------------------------------------------------------------------
__device__ __forceinline__ void gpool_body(int g,
                                           const __half* __restrict__ Xh,
                                           const int* __restrict__ gstart,
                                           float* __restrict__ pooled, int layer) {
    __shared__ float red[16][16][8];   // 8 KiB
    const int f8 = threadIdx.x & 15;   // col group: cols f8*8 .. f8*8+7
    const int qt = threadIdx.x >> 4;   // row phase 0..15
    const int s = gstart[g], e = gstart[g + 1];

    float acc[8];
#pragma unroll
    for (int j = 0; j < 8; ++j) acc[j] = 0.f;

    for (int n = s + qt; n < e; n += 16) {
        half8 v = ((const half8*)(Xh + (size_t)n * HIDDEN))[f8];
#pragma unroll
        for (int j = 0; j < 8; ++j) acc[j] += (float)v[j];
    }
#pragma unroll
    for (int j = 0; j < 8; ++j) red[qt][f8][j] = acc[j];
    __syncthreads();

    if (threadIdx.x < 128) {
        const int c = threadIdx.x;
        float sum = 0.f;
#pragma unroll
        for (int p = 0; p < 16; ++p) sum += red[p][c >> 3][c & 7];
        pooled[(size_t)g * (HIDDEN * N_LAYERS) + layer * HIDDEN + c] = sum;
    }
}

__global__ __launch_bounds__(256) void gpool_kernel(const __half* __restrict__ Xh,
                                                    const int* __restrict__ gstart,
                                                    float* __restrict__ pooled,
                                                    int layer) {
    gpool_body(blockIdx.x, Xh, gstart, pooled, layer);
}

// gather(l) + gpool(l-1) grid-split fusion (R16-confirmed): both consume the
// same mm2 output; pool blocks FIRST so their streaming rides under gather's
// latency-bound phase.
#define POOL_BLKS N_GRAPHS   // 512
__global__ __launch_bounds__(256) void gather_pool_kernel(const unsigned char* __restrict__ Xq,
                                                          const __half* __restrict__ Xh,
                                                          __half* __restrict__ Zh,
                                                          const int* __restrict__ row_ptr,
                                                          const int* __restrict__ csr_src,
                                                          const int* __restrict__ gstart,
                                                          float* __restrict__ pooled,
                                                          int prev_layer) {
    if (blockIdx.x < POOL_BLKS) {
        gpool_body(blockIdx.x, Xh, gstart, pooled, prev_layer);
        return;
    }
    int wave = ((blockIdx.x - POOL_BLKS) * 256 + threadIdx.x) >> 6;
    if (wave >= N_NODES) return;
    gather_body(wave, threadIdx.x & 63, Xq, Xh, Zh, row_ptr, csr_src);
}

// ---------------------------------------------------------------------------
// Fused wave-split MLP (R22 = R21 + pipelining). R9 counters: spill gone
// (VGPR 36, FETCH 12.8 MB, WRITE 37.5 MB = exact) but 1.0 TB/s effective ->
// latency-chain-bound: ~3 tiles/block, no overlap between tiles, each tile a
// serial HBM-load -> mm1 -> LDS -> barrier -> mm2 -> store chain. Fix:
//  (a) next-tile A prefetch (load t+stride issued before mm1(t)); VGPR ~52.
//  (b) MMF_BLOCKS 2048 -> 512 (~12 tiles/block) so the pipeline amortizes
//      fill/drain; 512 blocks = exactly 2/CU at the measured 49% occupancy.
// Single-barrier dbuf unchanged (R9-proven): wave reaches the hs[b] overwrite
// in iter k+2 only after the k+1 barrier, which all waves pass only after
// their iter-k reads.
// ---------------------------------------------------------------------------
#define MMF_BLOCKS 512
__global__ __launch_bounds__(512) void mlp_ws_kernel(const __half* __restrict__ A,
                                                     const __half* __restrict__ Wt1,
                                                     const __half* __restrict__ Wt2,
                                                     const float* __restrict__ b1,
                                                     const float* __restrict__ b2,
                                                     __half* __restrict__ C16,
                                                     unsigned char* __restrict__ Q8) {
    __shared__ _Float16 hs[2][16][128];   // 8 KiB, XOR-swizzled 16B chunks

    const int tid  = threadIdx.x;
    const int wv   = tid >> 6;         // 0..7: owned ct (16 output cols)
    const int lane = tid & 63;
    const int m    = lane & 15;
    const int q    = lane >> 4;
    const int NTILES = N_NODES / 16;   // 6250

    // per-wave weight slices + biases (register-resident, 40 VGPRs)
    half8 wf1[4], wf2[4];
    float bl1[4], bl2[4];
    {
        const half8* W1row = (const half8*)(Wt1 + (size_t)(wv * 16 + m) * HIDDEN);
        const half8* W2row = (const half8*)(Wt2 + (size_t)(wv * 16 + m) * HIDDEN);
#pragma unroll
        for (int c = 0; c < 4; ++c) { wf1[c] = W1row[c * 4 + q]; wf2[c] = W2row[c * 4 + q]; }
#pragma unroll
        for (int r = 0; r < 4; ++r) {
            bl1[r] = b1[wv * 16 + q * 4 + r];
            bl2[r] = b2[wv * 16 + q * 4 + r];
        }
    }

    // h-store address (swizzled): chunk (2wv + (q>>1)) ^ m, half-chunk q&1
    _Float16* hwr0 = &hs[0][m][(((2 * wv + (q >> 1)) ^ m) << 3) + ((q & 1) << 2)];
    _Float16* hwr1 = &hs[1][m][(((2 * wv + (q >> 1)) ^ m) << 3) + ((q & 1) << 2)];
    const _Float16* hrd0 = &hs[0][m][0];
    const _Float16* hrd1 = &hs[1][m][0];

    // prime tile 0
    int t = blockIdx.x;
    half8 a0, a1, a2, a3;
    {
        const half8* Arow = (const half8*)(A + (size_t)(t * 16 + m) * HIDDEN);
        a0 = Arow[q]; a1 = Arow[4 + q]; a2 = Arow[8 + q]; a3 = Arow[12 + q];
    }

    int buf = 0;
    while (true) {
        const int tn = t + MMF_BLOCKS;
        half8 n0, n1, n2, n3;
        if (tn < NTILES) {   // prefetch next tile (wave-uniform branch)
            const half8* Nrow = (const half8*)(A + (size_t)(tn * 16 + m) * HIDDEN);
            n0 = Nrow[q]; n1 = Nrow[4 + q]; n2 = Nrow[8 + q]; n3 = Nrow[12 + q];
        }

        // ---- mm1: h(:, wv-slice) = relu(z @ W1 + b1) -> swizzled LDS
        {
            floatx4 acc = {0.f, 0.f, 0.f, 0.f};
            acc = __builtin_amdgcn_mfma_f32_16x16x32_f16(wf1[0], a0, acc, 0, 0, 0);
            acc = __builtin_amdgcn_mfma_f32_16x16x32_f16(wf1[1], a1, acc, 0, 0, 0);
            acc = __builtin_amdgcn_mfma_f32_16x16x32_f16(wf1[2], a2, acc, 0, 0, 0);
            acc = __builtin_amdgcn_mfma_f32_16x16x32_f16(wf1[3], a3, acc, 0, 0, 0);
            half4v o;
#pragma unroll
            for (int r = 0; r < 4; ++r) o[r] = (_Float16)fmaxf(acc[r] + bl1[r], 0.f);
            *(half4v*)(buf ? hwr1 : hwr0) = o;
        }
        __syncthreads();

        // ---- mm2: read full h row fragments (swizzled), compute wv-slice
        {
            const _Float16* hr = buf ? hrd1 : hrd0;
            half8 h0 = *(const half8*)(hr + (((0 + q) ^ m) << 3));
            half8 h1 = *(const half8*)(hr + (((4 + q) ^ m) << 3));
            half8 h2 = *(const half8*)(hr + (((8 + q) ^ m) << 3));
            half8 h3 = *(const half8*)(hr + (((12 + q) ^ m) << 3));
            floatx4 acc = {0.f, 0.f, 0.f, 0.f};
            acc = __builtin_amdgcn_mfma_f32_16x16x32_f16(wf2[0], h0, acc, 0, 0, 0);
            acc = __builtin_amdgcn_mfma_f32_16x16x32_f16(wf2[1], h1, acc, 0, 0, 0);
            acc = __builtin_amdgcn_mfma_f32_16x16x32_f16(wf2[2], h2, acc, 0, 0, 0);
            acc = __builtin_amdgcn_mfma_f32_16x16x32_f16(wf2[3], h3, acc, 0, 0, 0);
            float v0 = fmaxf(acc[0] + bl2[0], 0.f);
            float v1 = fmaxf(acc[1] + bl2[1], 0.f);
            float v2 = fmaxf(acc[2] + bl2[2], 0.f);
            float v3 = fmaxf(acc[3] + bl2[3], 0.f);
            const size_t base = (size_t)(t * 16 + m) * HIDDEN + wv * 16 + q * 4;
            half4v o;
            o[0] = (_Float16)v0; o[1] = (_Float16)v1;
            o[2] = (_Float16)v2; o[3] = (_Float16)v3;
            *(half4v*)(C16 + base) = o;
            if (Q8) {
                unsigned r0 = 0;
                r0 = __builtin_amdgcn_cvt_pk_fp8_f32(v0, v1, r0, false);
                r0 = __builtin_amdgcn_cvt_pk_fp8_f32(v2, v3, r0, true);
                *(unsigned*)(Q8 + base) = r0;
            }
        }

        if (tn >= NTILES) break;
        t = tn;
        a0 = n0; a1 = n1; a2 = n2; a3 = n3;
        buf ^= 1;
    }
}

// ---------------------------------------------------------------------------
__global__ __launch_bounds__(128) void cls_kernel(const float* __restrict__ pooled,
                                                  const float* __restrict__ w1,
                                                  const float* __restrict__ b1,
                                                  const float* __restrict__ w2,
                                                  const float* __restrict__ b2,
                                                  const float* __restrict__ w3,
                                                  const float* __restrict__ b3,
                                                  float* __restrict__ out) {
    __shared__ float hin[HIDDEN * N_LAYERS];
    __shared__ float h1[HIDDEN];
    __shared__ float red[HIDDEN];
    const int g = blockIdx.x;
    const int t = threadIdx.x;

    for (int i = t; i < HIDDEN * N_LAYERS; i += 128)
        hin[i] = pooled[(size_t)g * (HIDDEN * N_LAYERS) + i];
    __syncthreads();

    float s = 0.f;
    for (int k = 0; k < HIDDEN * N_LAYERS; ++k) s += hin[k] * w1[(size_t)k * HIDDEN + t];
    s = fmaxf(s + b1[t], 0.f);
    h1[t] = s;
    __syncthreads();

    float s2 = 0.f;
    for (int k = 0; k < HIDDEN; ++k) s2 += h1[k] * w2[(size_t)k * HIDDEN + t];
    s2 = fmaxf(s2 + b2[t], 0.f);

    red[t] = s2 * w3[t];
    __syncthreads();
    for (int off = 64; off > 0; off >>= 1) {
        if (t < off) red[t] += red[t + off];
        __syncthreads();
    }
    if (t == 0) out[g] = red[0] + b3[0];
}

// ---------------------------------------------------------------------------
extern "C" void kernel_launch(void* const* d_in, const int* in_sizes, int n_in,
                              void* d_out, int out_size, void* d_ws, size_t ws_size,
                              hipStream_t stream) {
    const float* X     = (const float*)d_in[0];
    const int*   ei    = (const int*)d_in[1];
    const int*   batch = (const int*)d_in[2];
    const float* w1all = (const float*)d_in[3];
    const float* b1all = (const float*)d_in[4];
    const float* w2all = (const float*)d_in[5];
    const float* b2all = (const float*)d_in[6];
    const float* cw1   = (const float*)d_in[7];
    const float* cb1   = (const float*)d_in[8];
    const float* cw2   = (const float*)d_in[9];
    const float* cb2   = (const float*)d_in[10];
    const float* cw3   = (const float*)d_in[11];
    const float* cb3   = (const float*)d_in[12];
    float* out = (float*)d_out;

    const int* src = ei;
    const int* dst = ei + N_EDGES;

    char* p = (char*)d_ws;
    auto alloc2 = [&](size_t bytes) {
        char* r = p;
        p += (bytes + 255) & ~(size_t)255;
        return r;
    };
    __half* hA      = (__half*)alloc2((size_t)N_NODES * HIDDEN * sizeof(__half));
    __half* hB      = (__half*)alloc2((size_t)N_NODES * HIDDEN * sizeof(__half));
    __half* zh      = (__half*)alloc2((size_t)N_NODES * HIDDEN * sizeof(__half));
    unsigned char* qbuf = (unsigned char*)alloc2((size_t)N_NODES * HIDDEN);
    __half* wt1     = (__half*)alloc2((size_t)N_LAYERS * HIDDEN * HIDDEN * sizeof(__half));
    __half* wt2     = (__half*)alloc2((size_t)N_LAYERS * HIDDEN * HIDDEN * sizeof(__half));
    int2*   wedge   = (int2*)alloc2((size_t)N_EDGES * sizeof(int2));
    int*    csr     = (int*)alloc2((size_t)N_EDGES * sizeof(int));
    int*    rowp    = (int*)alloc2((size_t)(N_NODES + 1) * sizeof(int));
    int*    counts  = (int*)alloc2((size_t)PLACE_BLOCKS * N_WIN * sizeof(int));
    int*    offsets = (int*)alloc2((size_t)PLACE_BLOCKS * N_WIN * sizeof(int));
    int*    colsum  = (int*)alloc2((size_t)N_WIN * sizeof(int));
    int*    gstart  = (int*)alloc2((size_t)(N_GRAPHS + 1) * sizeof(int));
    float*  pooled  = (float*)alloc2((size_t)N_GRAPHS * HIDDEN * N_LAYERS * sizeof(float));

    // CSR build: count -> column scan -> place -> fused per-window csr
    win_count_kernel<<<PLACE_BLOCKS, 256, 0, stream>>>(dst, counts);
    win_scan1_kernel<<<N_WIN, 128, 0, stream>>>(counts, offsets, colsum);
    win_place_kernel<<<PLACE_BLOCKS, 512, 0, stream>>>(src, dst, offsets, colsum, wedge);
    win_csr_kernel<<<N_WIN, 512, 0, stream>>>(wedge, colsum, rowp, csr);

    // fused prep: X conversions + weight transpose + graph-boundary search
    prep_kernel<<<PREP_BLOCKS, 256, 0, stream>>>(X, hA, qbuf, w1all, w2all, wt1, wt2,
                                                 batch, gstart);

    const int gat_grid = (N_NODES + 3) / 4;           // 25000

    __half* hcur = hA;
    for (int l = 0; l < N_LAYERS; ++l) {
        __half* hnext = (l & 1) ? hA : hB;
        const bool emit = (l < N_LAYERS - 1);
        if (l == 0) {
            gather_kernel<<<gat_grid, 256, 0, stream>>>(qbuf, hcur, zh, rowp, csr);
        } else {
            // gather(l) + gpool(l-1): both consume hcur (= mm2 output of l-1)
            gather_pool_kernel<<<gat_grid + POOL_BLKS, 256, 0, stream>>>(
                qbuf, hcur, zh, rowp, csr, gstart, pooled, l - 1);
        }
        mlp_ws_kernel<<<MMF_BLOCKS, 512, 0, stream>>>(zh,
                                                      wt1 + (size_t)l * HIDDEN * HIDDEN,
                                                      wt2 + (size_t)l * HIDDEN * HIDDEN,
                                                      b1all + (size_t)l * HIDDEN,
                                                      b2all + (size_t)l * HIDDEN,
                                                      hnext,
                                                      emit ? qbuf : (unsigned char*)nullptr);
        hcur = hnext;
    }

    gpool_kernel<<<N_GRAPHS, 256, 0, stream>>>(hcur, gstart, pooled, N_LAYERS - 1);
    cls_kernel<<<N_GRAPHS, 128, 0, stream>>>(pooled, cw1, cb1, cw2, cb2, cw3, cb3, out);
}